// Round 1
// baseline (1410.598 us; speedup 1.0000x reference)
//
#include <hip/hip_runtime.h>
#include <cstddef>

// PointNet++ set-abstraction pipeline (B=16, N=4096, HC=64), fp32.
// Stages: SA1(npoint=256,r=0.2,ns=32, 6->64->128), SA2(128,0.25,64, 131->128->256),
//         SA3(group_all, 259->256->512).
// Key tricks: per-point projection + gather for layer1; max/min-of-preact + monotone
// BN/ReLU for the k-maxpool (never materialize layer-2 activations); slotted atomic
// BN statistics with in-block finalization (train-mode BN over (B,S,K)).

#define EPSB 1e-5f
constexpr int SLOTS1 = 16;   // stats arena slots for layer-1 stats
constexpr int SLOTS2 = 64;   // stats arena slots for layer-2 stats
constexpr int BATCH = 16;

// ---------------- FPS ----------------
// Replicates jax scan: idx[0]=0; dist=min(dist,|x-c|^2); next=argmax (first-index ties).
template<int N, int NPOINT, int THREADS>
__global__ __launch_bounds__(THREADS)
void fps_kernel(const float* __restrict__ xyz, int bStride, int cStride, int nStride,
                float* __restrict__ nxyz /* (B,NPOINT,3) */,
                float* __restrict__ lxyz /* (B,3,NPOINT) out */)
{
    constexpr int PT = N / THREADS;
    constexpr int NW = THREADS / 64;
    const int b = blockIdx.x, t = threadIdx.x;
    const float* xb = xyz + (size_t)b * bStride;
    float px[PT], py[PT], pz[PT], dist[PT];
#pragma unroll
    for (int i = 0; i < PT; ++i) {
        int p = t + i * THREADS;
        px[i] = xb[(size_t)0 * cStride + (size_t)p * nStride];
        py[i] = xb[(size_t)1 * cStride + (size_t)p * nStride];
        pz[i] = xb[(size_t)2 * cStride + (size_t)p * nStride];
        dist[i] = 1e10f;
    }
    __shared__ float sred[NW][5];
    __shared__ float scur[3];
    if (t == 0) {  // selection 0 is always index 0 (owned by thread 0, slot 0)
        scur[0] = px[0]; scur[1] = py[0]; scur[2] = pz[0];
        nxyz[(size_t)(b * NPOINT) * 3 + 0] = px[0];
        nxyz[(size_t)(b * NPOINT) * 3 + 1] = py[0];
        nxyz[(size_t)(b * NPOINT) * 3 + 2] = pz[0];
        lxyz[(size_t)b * 3 * NPOINT + 0 * NPOINT] = px[0];
        lxyz[(size_t)b * 3 * NPOINT + 1 * NPOINT] = py[0];
        lxyz[(size_t)b * 3 * NPOINT + 2 * NPOINT] = pz[0];
    }
    __syncthreads();
    for (int it = 1; it < NPOINT; ++it) {
        float cx = scur[0], cy = scur[1], cz = scur[2];
        float bv = -1.0f; int bi = 0; float bx = 0.f, by = 0.f, bz = 0.f;
#pragma unroll
        for (int i = 0; i < PT; ++i) {
            float dx = px[i] - cx, dy = py[i] - cy, dz = pz[i] - cz;
            float d = dx * dx + dy * dy + dz * dz;
            float nd = fminf(dist[i], d);
            dist[i] = nd;
            if (nd > bv) { bv = nd; bi = t + i * THREADS; bx = px[i]; by = py[i]; bz = pz[i]; }
        }
#pragma unroll
        for (int off = 32; off > 0; off >>= 1) {
            float ov = __shfl_down(bv, off);
            int   oi = __shfl_down(bi, off);
            float ox = __shfl_down(bx, off);
            float oy = __shfl_down(by, off);
            float oz = __shfl_down(bz, off);
            if (ov > bv || (ov == bv && oi < bi)) { bv = ov; bi = oi; bx = ox; by = oy; bz = oz; }
        }
        if constexpr (THREADS > 64) {
            if ((t & 63) == 0) {
                int w = t >> 6;
                sred[w][0] = bv; sred[w][1] = __int_as_float(bi);
                sred[w][2] = bx; sred[w][3] = by; sred[w][4] = bz;
            }
            __syncthreads();
            if (t < 64) {
                if (t < NW) {
                    bv = sred[t][0]; bi = __float_as_int(sred[t][1]);
                    bx = sred[t][2]; by = sred[t][3]; bz = sred[t][4];
                } else { bv = -1.0f; bi = 0x7fffffff; bx = by = bz = 0.f; }
#pragma unroll
                for (int off = 32; off > 0; off >>= 1) {
                    float ov = __shfl_down(bv, off);
                    int   oi = __shfl_down(bi, off);
                    float ox = __shfl_down(bx, off);
                    float oy = __shfl_down(by, off);
                    float oz = __shfl_down(bz, off);
                    if (ov > bv || (ov == bv && oi < bi)) { bv = ov; bi = oi; bx = ox; by = oy; bz = oz; }
                }
            }
        }
        if (t == 0) {
            scur[0] = bx; scur[1] = by; scur[2] = bz;
            nxyz[(size_t)(b * NPOINT + it) * 3 + 0] = bx;
            nxyz[(size_t)(b * NPOINT + it) * 3 + 1] = by;
            nxyz[(size_t)(b * NPOINT + it) * 3 + 2] = bz;
            lxyz[(size_t)b * 3 * NPOINT + 0 * NPOINT + it] = bx;
            lxyz[(size_t)b * 3 * NPOINT + 1 * NPOINT + it] = by;
            lxyz[(size_t)b * 3 * NPOINT + 2 * NPOINT + it] = bz;
        }
        __syncthreads();
    }
}

// ---------------- SA1 per-point projection: p1[b,n,64] = [xyz,pts]·W1 + b1 ----------------
__global__ __launch_bounds__(256)
void project6_kernel(const float* __restrict__ xyz, const float* __restrict__ pts,
                     const float* __restrict__ W, const float* __restrict__ bias,
                     float* __restrict__ outp)
{
    int idx = blockIdx.x * 256 + threadIdx.x;     // (b, n, d), d fastest (64)
    int d = idx & 63;
    int n = (idx >> 6) & 4095;
    int b = idx >> 18;
    const float* xb = xyz + (size_t)b * 3 * 4096 + n;
    const float* pb = pts + (size_t)b * 3 * 4096 + n;
    float a0 = xb[0], a1 = xb[4096], a2 = xb[2 * 4096];
    float a3 = pb[0], a4 = pb[4096], a5 = pb[2 * 4096];
    float acc = bias[d];
    acc += a0 * W[d] + a1 * W[64 + d] + a2 * W[128 + d];
    acc += a3 * W[192 + d] + a4 * W[256 + d] + a5 * W[320 + d];
    outp[idx] = acc;
}

// ---------------- Ball query (one wave per ball) + center projection q ----------------
template<int NS>
__global__ __launch_bounds__(64)
void ballquery_kernel(const float* __restrict__ xyz, int bStride, int cStride, int nStride, int N,
                      const float* __restrict__ nxyz, int S, float r2,
                      int* __restrict__ gi,
                      const float* __restrict__ W, int D, float* __restrict__ q)
{
    int bs = blockIdx.x;
    int b = bs / S;
    int l = threadIdx.x;
    float cx = nxyz[(size_t)bs * 3 + 0], cy = nxyz[(size_t)bs * 3 + 1], cz = nxyz[(size_t)bs * 3 + 2];
    float s2 = cx * cx + cy * cy + cz * cz;
    const float* xb = xyz + (size_t)b * bStride;
    int cnt = 0;
    int first = N - 1;   // matches jnp clip behavior if the ball were empty
    int* go = gi + (size_t)bs * NS;
    for (int base = 0; base < N; base += 64) {
        int n = base + l;
        float x = xb[(size_t)0 * cStride + (size_t)n * nStride];
        float y = xb[(size_t)1 * cStride + (size_t)n * nStride];
        float z = xb[(size_t)2 * cStride + (size_t)n * nStride];
        float x2 = x * x + y * y + z * z;
        float dot = cx * x + cy * y + cz * z;
        float sqr = (s2 + x2) - 2.0f * dot;      // reference expansion form
        bool pass = (sqr <= r2);
        unsigned long long m = __ballot(pass);
        if (cnt == 0 && m) first = base + (__ffsll((unsigned long long)m) - 1);
        int pos = cnt + __popcll(m & ((1ull << l) - 1ull));
        if (pass && pos < NS) go[pos] = n;
        cnt += __popcll(m);
        if (cnt >= NS) break;
    }
    if (cnt < NS && l >= cnt && l < NS) go[l] = first;  // pad with first hit
    for (int d = l; d < D; d += 64)
        q[(size_t)bs * D + d] = cx * W[d] + cy * W[D + d] + cz * W[2 * D + d];
}

// ---------------- BN1 statistics over gathered layer-1 preacts ----------------
__global__ __launch_bounds__(256)
void stats_gather_kernel(const float* __restrict__ p, const float* __restrict__ q,
                         const int* __restrict__ gi, int S, int K, int N, int C,
                         float* __restrict__ slots)
{
    int R = 256 / C;
    int c = threadIdx.x % C;
    int r = threadIdx.x / C;
    int M = BATCH * S * K;
    float sum = 0.f, sq = 0.f;
    for (int j = blockIdx.x * R + r; j < M; j += gridDim.x * R) {
        int g = gi[j];
        int bs = j / K;
        int bb = bs / S;
        float v = p[(size_t)(bb * N + g) * C + c] - q[(size_t)bs * C + c];
        sum += v; sq += v * v;
    }
    __shared__ float red[2][4][128];
    red[0][r][c] = sum; red[1][r][c] = sq;
    __syncthreads();
    if (threadIdx.x < C) {
        float s0 = 0.f, s1 = 0.f;
        for (int i = 0; i < R; ++i) { s0 += red[0][i][threadIdx.x]; s1 += red[1][i][threadIdx.x]; }
        int slot = blockIdx.x & (SLOTS1 - 1);
        atomicAdd(&slots[(size_t)(slot * 2 + 0) * C + threadIdx.x], s0);
        atomicAdd(&slots[(size_t)(slot * 2 + 1) * C + threadIdx.x], s1);
    }
}

// ---------------- BN1 statistics over raw rows (SA3) ----------------
__global__ __launch_bounds__(256)
void stats_raw_kernel(const float* __restrict__ h, int M, int C, float* __restrict__ slots)
{
    int c = threadIdx.x;   // C == 256
    float sum = 0.f, sq = 0.f;
    for (int m = blockIdx.x; m < M; m += gridDim.x) {
        float v = h[(size_t)m * C + c];
        sum += v; sq += v * v;
    }
    int slot = blockIdx.x & (SLOTS1 - 1);
    atomicAdd(&slots[(size_t)(slot * 2 + 0) * C + c], sum);
    atomicAdd(&slots[(size_t)(slot * 2 + 1) * C + c], sq);
}

// ---------------- Tiled projection GEMM (SA2 p2, SA3 layer-1) ----------------
// out[b,n,:] = [xyz(b,n,0:3), feat(b,n,0:CF)]·W + bias   (K = CF+3, zero-padded panels)
template<int COUTB>
__global__ __launch_bounds__(512)
void proj_gemm_kernel(const float* __restrict__ xyzsrc, const float* __restrict__ featsrc,
                      int N, int CF,
                      const float* __restrict__ W, int coutFull,
                      const float* __restrict__ bias, float* __restrict__ outp)
{
    constexpr int BK = 32, BKP = 36, TK = 4, TC = 4, THREADS = 512, ROWS = 64;
    constexpr int C2G = COUTB / TC;
    static_assert(C2G * (ROWS / TK) == THREADS, "thread shape");
    __shared__ __attribute__((aligned(16))) float al[ROWS][BKP];
    __shared__ __attribute__((aligned(16))) float wl[COUTB][BKP];
    const int NCH = coutFull / COUTB;
    const int chunk = blockIdx.x % NCH;
    const int rb = blockIdx.x / NCH;
    const int m0 = rb * ROWS;
    const int c2_0 = chunk * COUTB;
    const int K = CF + 3;
    const int tid = threadIdx.x;
    const int c2g = tid % C2G, kt = tid / C2G;
    float acc[TK][TC];
#pragma unroll
    for (int i = 0; i < TK; ++i)
#pragma unroll
        for (int j = 0; j < TC; ++j) acc[i][j] = 0.f;
    const int npan = (K + BK - 1) / BK;
    for (int pan = 0; pan < npan; ++pan) {
        __syncthreads();
        const int cbase = pan * BK;
        for (int e = tid; e < ROWS * BK; e += THREADS) {
            int rl = e / BK, cl = e % BK;
            int c = cbase + cl;
            int m = m0 + rl;
            int bb = m / N, n = m % N;
            float v = 0.f;
            if (c < 3) v = xyzsrc[(size_t)(bb * N + n) * 3 + c];
            else if (c < K) v = featsrc[(size_t)(bb * N + n) * CF + (c - 3)];
            al[rl][cl] = v;
        }
        for (int e = tid; e < COUTB * BK; e += THREADS) {
            int c2 = e % COUTB, cl = e / COUTB;
            int c = cbase + cl;
            wl[c2][cl] = (c < K) ? W[(size_t)c * coutFull + c2_0 + c2] : 0.f;
        }
        __syncthreads();
#pragma unroll
        for (int cl = 0; cl < BK; cl += 4) {
            float4 av[TK], wv[TC];
#pragma unroll
            for (int i = 0; i < TK; ++i) av[i] = *(const float4*)&al[kt * TK + i][cl];
#pragma unroll
            for (int j = 0; j < TC; ++j) wv[j] = *(const float4*)&wl[c2g + j * C2G][cl];
#pragma unroll
            for (int i = 0; i < TK; ++i)
#pragma unroll
                for (int j = 0; j < TC; ++j)
                    acc[i][j] += av[i].x * wv[j].x + av[i].y * wv[j].y
                               + av[i].z * wv[j].z + av[i].w * wv[j].w;
        }
    }
#pragma unroll
    for (int j = 0; j < TC; ++j) {
        float bb_ = bias[c2_0 + c2g + j * C2G];
#pragma unroll
        for (int i = 0; i < TK; ++i) {
            int m = m0 + kt * TK + i;
            outp[(size_t)m * coutFull + c2_0 + c2g + j * C2G] = acc[i][j] + bb_;
        }
    }
}

// ---------------- Fused layer-2: gather -> BN1+ReLU -> GEMM -> max/min over k + BN2 stats ----
// gather mode (gi!=null): rows p[b*N + gi[bs*K+k]], minus q[bs]; identity mode: rows p[b*K+k].
// Emits per-(block-object, c2) max & min of preact (+bias) and slotted per-channel sum/sumsq.
template<int K, int CIN, int COUTB, int TK, int TC, int THREADS>
__global__ __launch_bounds__(THREADS)
void gather_gemm_kernel(const float* __restrict__ p, const float* __restrict__ q,
                        const int* __restrict__ gi, int S, int NCH, int N,
                        const float* __restrict__ st1, float m1count,
                        const float* __restrict__ g1, const float* __restrict__ be1,
                        const float* __restrict__ W2, int coutFull,
                        const float* __restrict__ b2,
                        float* __restrict__ st2,
                        float* __restrict__ mx, float* __restrict__ mn)
{
    constexpr int BK = 32, BKP = 36;
    constexpr int C2G = COUTB / TC;
    constexpr int KTG = K / TK;
    constexpr int NW = THREADS / 64;
    constexpr int KPW = 64 / C2G;
    static_assert(C2G * KTG == THREADS, "thread shape");
    __shared__ float ss_scale[CIN], ss_shift[CIN];
    __shared__ __attribute__((aligned(16))) float hl[K][BKP];
    __shared__ __attribute__((aligned(16))) float wl[COUTB][BKP];
    __shared__ float red[4][NW][COUTB];

    const int chunk = blockIdx.x % NCH;
    const int bs = blockIdx.x / NCH;
    const int b = bs / S;
    const int tid = threadIdx.x;
    const int c2_0 = chunk * COUTB;
    const int c2g = tid % C2G, kt = tid / C2G;
    const bool gather = (gi != nullptr);

    // finalize BN1 from slotted stats
    for (int c = tid; c < CIN; c += THREADS) {
        float s0 = 0.f, s1 = 0.f;
        for (int sl = 0; sl < SLOTS1; ++sl) {
            s0 += st1[(size_t)(sl * 2 + 0) * CIN + c];
            s1 += st1[(size_t)(sl * 2 + 1) * CIN + c];
        }
        float mean = s0 / m1count;
        float var = s1 / m1count - mean * mean;
        float inv = 1.0f / sqrtf(var + EPSB);
        float sc = g1[c] * inv;
        ss_scale[c] = sc;
        ss_shift[c] = be1[c] - sc * mean;
    }

    float acc[TK][TC];
#pragma unroll
    for (int i = 0; i < TK; ++i)
#pragma unroll
        for (int j = 0; j < TC; ++j) acc[i][j] = 0.f;

    for (int pan = 0; pan < CIN / BK; ++pan) {
        __syncthreads();   // also covers ss_* readiness on first pass
        const int cbase = pan * BK;
        for (int e = tid; e < K * BK; e += THREADS) {
            int k = e / BK, cl = e % BK;
            int c1 = cbase + cl;
            int row = gather ? (b * N + gi[(size_t)bs * K + k]) : (b * K + k);
            float v = p[(size_t)row * CIN + c1];
            if (q) v -= q[(size_t)bs * CIN + c1];
            v = fmaxf(ss_scale[c1] * v + ss_shift[c1], 0.f);
            hl[k][cl] = v;
        }
        for (int e = tid; e < COUTB * BK; e += THREADS) {
            int c2 = e % COUTB, cl = e / COUTB;
            wl[c2][cl] = W2[(size_t)(cbase + cl) * coutFull + c2_0 + c2];
        }
        __syncthreads();
#pragma unroll
        for (int cl = 0; cl < BK; cl += 4) {
            float4 av[TK], wv[TC];
#pragma unroll
            for (int i = 0; i < TK; ++i) av[i] = *(const float4*)&hl[kt * TK + i][cl];
#pragma unroll
            for (int j = 0; j < TC; ++j) wv[j] = *(const float4*)&wl[c2g + j * C2G][cl];
#pragma unroll
            for (int i = 0; i < TK; ++i)
#pragma unroll
                for (int j = 0; j < TC; ++j)
                    acc[i][j] += av[i].x * wv[j].x + av[i].y * wv[j].y
                               + av[i].z * wv[j].z + av[i].w * wv[j].w;
        }
    }

    // per-thread partials over its TK samples (preact includes bias)
    float psum[TC], psq[TC], pmx[TC], pmn[TC];
#pragma unroll
    for (int j = 0; j < TC; ++j) {
        float bb_ = b2[c2_0 + c2g + j * C2G];
        float s = 0.f, ss = 0.f, mx_ = -3.4e38f, mn_ = 3.4e38f;
#pragma unroll
        for (int i = 0; i < TK; ++i) {
            float v = acc[i][j] + bb_;
            s += v; ss += v * v; mx_ = fmaxf(mx_, v); mn_ = fminf(mn_, v);
        }
        psum[j] = s; psq[j] = ss; pmx[j] = mx_; pmn[j] = mn_;
    }
    // shuffle-reduce across kt groups within each wave
#pragma unroll
    for (int off = C2G; off < 64; off <<= 1) {
#pragma unroll
        for (int j = 0; j < TC; ++j) {
            psum[j] += __shfl_down(psum[j], off);
            psq[j]  += __shfl_down(psq[j], off);
            pmx[j] = fmaxf(pmx[j], __shfl_down(pmx[j], off));
            pmn[j] = fminf(pmn[j], __shfl_down(pmn[j], off));
        }
    }
    if ((kt % KPW) == 0) {
        int wrow = kt / KPW;
#pragma unroll
        for (int j = 0; j < TC; ++j) {
            int c2 = c2g + j * C2G;
            red[0][wrow][c2] = psum[j];
            red[1][wrow][c2] = psq[j];
            red[2][wrow][c2] = pmx[j];
            red[3][wrow][c2] = pmn[j];
        }
    }
    __syncthreads();
    if (tid < COUTB) {
        float s = 0.f, ss = 0.f, mxv = -3.4e38f, mnv = 3.4e38f;
        for (int w = 0; w < NW; ++w) {
            s += red[0][w][tid]; ss += red[1][w][tid];
            mxv = fmaxf(mxv, red[2][w][tid]);
            mnv = fminf(mnv, red[3][w][tid]);
        }
        int slot = blockIdx.x & (SLOTS2 - 1);
        atomicAdd(&st2[(size_t)(slot * 2 + 0) * coutFull + c2_0 + tid], s);
        atomicAdd(&st2[(size_t)(slot * 2 + 1) * coutFull + c2_0 + tid], ss);
        mx[(size_t)bs * coutFull + c2_0 + tid] = mxv;
        mn[(size_t)bs * coutFull + c2_0 + tid] = mnv;
    }
}

// ---------------- Finalize BN2, apply to max/min, ReLU, write feat + transposed out --------
__global__ __launch_bounds__(256)
void apply_kernel(const float* __restrict__ st2, int C, float m2count,
                  const float* __restrict__ g2, const float* __restrict__ be2,
                  const float* __restrict__ mx, const float* __restrict__ mn,
                  int S, float* __restrict__ feat, float* __restrict__ outT,
                  int total, float* __restrict__ zero48)
{
    __shared__ float sc[512], sh[512];
    for (int c = threadIdx.x; c < C; c += 256) {
        float s0 = 0.f, s1 = 0.f;
        for (int sl = 0; sl < SLOTS2; ++sl) {
            s0 += st2[(size_t)(sl * 2 + 0) * C + c];
            s1 += st2[(size_t)(sl * 2 + 1) * C + c];
        }
        float mean = s0 / m2count;
        float var = s1 / m2count - mean * mean;
        float inv = 1.0f / sqrtf(var + EPSB);
        float scl = g2[c] * inv;
        sc[c] = scl; sh[c] = be2[c] - scl * mean;
    }
    __syncthreads();
    if (zero48 && blockIdx.x == 0 && threadIdx.x < 48) zero48[threadIdx.x] = 0.f;
    for (int e = blockIdx.x * 256 + threadIdx.x; e < total; e += gridDim.x * 256) {
        int c = e % C;
        int s = (e / C) % S;
        int b = e / (C * S);
        float scl = sc[c];
        float v = (scl >= 0.f) ? mx[e] : mn[e];   // maxpool commutes: sign picks extremum
        float y = fmaxf(scl * v + sh[c], 0.f);
        if (feat) feat[e] = y;
        outT[((size_t)b * C + c) * S + s] = y;
    }
}

extern "C" void kernel_launch(void* const* d_in, const int* in_sizes, int n_in,
                              void* d_out, int out_size, void* d_ws, size_t ws_size,
                              hipStream_t stream)
{
    (void)in_sizes; (void)n_in; (void)out_size; (void)ws_size;
    const float* l0_xyz = (const float*)d_in[0];
    const float* l0_pts = (const float*)d_in[1];
    const float* w11 = (const float*)d_in[2];  const float* b11 = (const float*)d_in[3];
    const float* g11 = (const float*)d_in[4];  const float* be11 = (const float*)d_in[5];
    const float* w12 = (const float*)d_in[6];  const float* b12 = (const float*)d_in[7];
    const float* g12 = (const float*)d_in[8];  const float* be12 = (const float*)d_in[9];
    const float* w21 = (const float*)d_in[10]; const float* b21 = (const float*)d_in[11];
    const float* g21 = (const float*)d_in[12]; const float* be21 = (const float*)d_in[13];
    const float* w22 = (const float*)d_in[14]; const float* b22 = (const float*)d_in[15];
    const float* g22 = (const float*)d_in[16]; const float* be22 = (const float*)d_in[17];
    const float* w31 = (const float*)d_in[18]; const float* b31 = (const float*)d_in[19];
    const float* g31 = (const float*)d_in[20]; const float* be31 = (const float*)d_in[21];
    const float* w32 = (const float*)d_in[22]; const float* b32 = (const float*)d_in[23];
    const float* g32 = (const float*)d_in[24]; const float* be32 = (const float*)d_in[25];

    float* out = (float*)d_out;
    float* o_l1xyz = out;                 // (16,3,256)
    float* o_l1pts = out + 12288;         // (16,128,256)
    float* o_l2xyz = out + 536576;        // (16,3,128)
    float* o_l2pts = out + 542720;        // (16,256,128)
    float* o_l3xyz = out + 1067008;       // (16,3,1)
    float* o_x     = out + 1067056;       // (16,512)

    char* ws = (char*)d_ws;
    size_t off = 0;
    auto alloc = [&](size_t elems) {
        void* r = ws + off;
        off += ((elems * 4 + 255) & ~(size_t)255);
        return r;
    };
    float* nxyz1 = (float*)alloc(12288);
    float* nxyz2 = (float*)alloc(6144);
    int*   gi1   = (int*)alloc(131072);
    int*   gi2   = (int*)alloc(131072);
    float* p1    = (float*)alloc(4194304);
    float* q1    = (float*)alloc(262144);
    float* feat1 = (float*)alloc(524288);
    float* mx1   = (float*)alloc(524288);
    float* mn1   = (float*)alloc(524288);
    float* p2    = (float*)alloc(524288);
    float* q2    = (float*)alloc(262144);
    float* feat2 = (float*)alloc(524288);
    float* mx2   = (float*)alloc(524288);
    float* mn2   = (float*)alloc(524288);
    float* h31   = (float*)alloc(524288);
    float* mx3   = (float*)alloc(8192);
    float* mn3   = (float*)alloc(8192);
    float* stats = (float*)alloc(129024);
    float* st1a = stats;                 // 16*2*64
    float* st2a = st1a + 2048;           // 64*2*128
    float* st1b = st2a + 16384;          // 16*2*128
    float* st2b = st1b + 4096;           // 64*2*256
    float* st3a = st2b + 32768;          // 16*2*256
    float* st3b = st3a + 8192;           // 64*2*512

    hipMemsetAsync(stats, 0, 129024 * sizeof(float), stream);

    // ---- SA1 ----
    fps_kernel<4096, 256, 512><<<16, 512, 0, stream>>>(l0_xyz, 3 * 4096, 4096, 1, nxyz1, o_l1xyz);
    project6_kernel<<<16384, 256, 0, stream>>>(l0_xyz, l0_pts, w11, b11, p1);
    ballquery_kernel<32><<<4096, 64, 0, stream>>>(l0_xyz, 3 * 4096, 4096, 1, 4096,
                                                  nxyz1, 256, 0.04f, gi1, w11, 64, q1);
    stats_gather_kernel<<<256, 256, 0, stream>>>(p1, q1, gi1, 256, 32, 4096, 64, st1a);
    gather_gemm_kernel<32, 64, 128, 4, 4, 256><<<4096, 256, 0, stream>>>(
        p1, q1, gi1, 256, 1, 4096, st1a, 131072.0f, g11, be11, w12, 128, b12, st2a, mx1, mn1);
    apply_kernel<<<128, 256, 0, stream>>>(st2a, 128, 131072.0f, g12, be12, mx1, mn1,
                                          256, feat1, o_l1pts, 524288, nullptr);

    // ---- SA2 ----
    fps_kernel<256, 128, 64><<<16, 64, 0, stream>>>(nxyz1, 768, 1, 3, nxyz2, o_l2xyz);
    proj_gemm_kernel<128><<<64, 512, 0, stream>>>(nxyz1, feat1, 256, 128, w21, 128, b21, p2);
    ballquery_kernel<64><<<2048, 64, 0, stream>>>(nxyz1, 768, 1, 3, 256,
                                                  nxyz2, 128, 0.0625f, gi2, w21, 128, q2);
    stats_gather_kernel<<<256, 256, 0, stream>>>(p2, q2, gi2, 128, 64, 256, 128, st1b);
    gather_gemm_kernel<64, 128, 128, 4, 4, 512><<<4096, 512, 0, stream>>>(
        p2, q2, gi2, 128, 2, 256, st1b, 131072.0f, g21, be21, w22, 256, b22, st2b, mx2, mn2);
    apply_kernel<<<128, 256, 0, stream>>>(st2b, 256, 131072.0f, g22, be22, mx2, mn2,
                                          128, feat2, o_l2pts, 524288, nullptr);

    // ---- SA3 (group_all) ----
    proj_gemm_kernel<128><<<64, 512, 0, stream>>>(nxyz2, feat2, 128, 256, w31, 256, b31, h31);
    stats_raw_kernel<<<128, 256, 0, stream>>>(h31, 2048, 256, st3a);
    gather_gemm_kernel<128, 256, 64, 4, 4, 512><<<128, 512, 0, stream>>>(
        h31, nullptr, nullptr, 1, 8, 0, st3a, 2048.0f, g31, be31, w32, 512, b32, st3b, mx3, mn3);
    apply_kernel<<<32, 256, 0, stream>>>(st3b, 512, 2048.0f, g32, be32, mx3, mn3,
                                         1, nullptr, o_x, 8192, o_l3xyz);
}

// Round 2
// 1098.602 us; speedup vs baseline: 1.2840x; 1.2840x over previous
//
#include <hip/hip_runtime.h>
#include <cstddef>

// PointNet++ set-abstraction pipeline (B=16, N=4096, HC=64), fp32.
// Stages: SA1(npoint=256,r=0.2,ns=32, 6->64->128), SA2(128,0.25,64, 131->128->256),
//         SA3(group_all, 259->256->512).
// R2: FPS rewritten — packed u64 (dist,~idx) argmax key, LDS coord table,
// single barrier per round (parity double-buffered partials), single-wave SA2 FPS.

#define EPSB 1e-5f
constexpr int SLOTS1 = 16;   // stats arena slots for layer-1 stats
constexpr int SLOTS2 = 64;   // stats arena slots for layer-2 stats
constexpr int BATCH = 16;

static __device__ __forceinline__ unsigned long long umax64(unsigned long long a,
                                                            unsigned long long b)
{
    return a > b ? a : b;
}

// ---------------- FPS ----------------
// Replicates jax scan: idx[0]=0; dist=min(dist,|x-c|^2); next=argmax (first-index ties).
// Key packing: hi = float bits of dist (dist>=0 so uint order == float order),
//              lo = ~gidx (max -> smallest index on ties, == jnp.argmax semantics).
template<int N, int NPOINT, int THREADS>
__global__ __launch_bounds__(THREADS)
void fps_kernel(const float* __restrict__ xyz, int bStride, int cStride, int nStride,
                float* __restrict__ nxyz /* (B,NPOINT,3) */,
                float* __restrict__ lxyz /* (B,3,NPOINT) out */)
{
    constexpr int PT = N / THREADS;
    constexpr int NW = THREADS / 64;
    const int b = blockIdx.x, t = threadIdx.x;
    const float* xb = xyz + (size_t)b * bStride;

    __shared__ float sx[N], sy[N], sz[N];
    __shared__ unsigned long long red[2][NW > 1 ? NW : 1];
    __shared__ int sel[NPOINT];

    float px[PT], py[PT], pz[PT], dist[PT];
#pragma unroll
    for (int i = 0; i < PT; ++i) {
        int p = t + i * THREADS;
        px[i] = xb[(size_t)0 * cStride + (size_t)p * nStride];
        py[i] = xb[(size_t)1 * cStride + (size_t)p * nStride];
        pz[i] = xb[(size_t)2 * cStride + (size_t)p * nStride];
        sx[p] = px[i]; sy[p] = py[i]; sz[p] = pz[i];
        dist[i] = 1e10f;
    }
    if (t == 0) sel[0] = 0;
    __syncthreads();

    float cx = sx[0], cy = sy[0], cz = sz[0];
    for (int it = 1; it < NPOINT; ++it) {
        unsigned long long best = 0ull;
#pragma unroll
        for (int i = 0; i < PT; ++i) {
            float dx = px[i] - cx, dy = py[i] - cy, dz = pz[i] - cz;
            float d = __builtin_fmaf(dx, dx, __builtin_fmaf(dy, dy, dz * dz));
            float nd = fminf(dist[i], d);
            dist[i] = nd;
            unsigned long long k =
                ((unsigned long long)__float_as_uint(nd) << 32) |
                (unsigned int)(~(t + i * THREADS));
            best = umax64(best, k);
        }
        int widx;
        if constexpr (NW > 1) {
            // wave-level reduce, result in lane 0
#pragma unroll
            for (int off = 32; off > 0; off >>= 1)
                best = umax64(best, __shfl_down(best, off));
            const int pb = it & 1;
            if ((t & 63) == 0) red[pb][t >> 6] = best;
            __syncthreads();
            unsigned long long m = red[pb][0];
#pragma unroll
            for (int w = 1; w < NW; ++w) m = umax64(m, red[pb][w]);
            widx = (int)(~(unsigned int)m);
        } else {
            // single wave: butterfly so ALL lanes hold the winner; no barrier at all
#pragma unroll
            for (int off = 1; off < 64; off <<= 1)
                best = umax64(best, __shfl_xor(best, off));
            widx = (int)(~(unsigned int)best);
        }
        if (t == 0) sel[it] = widx;
        cx = sx[widx]; cy = sy[widx]; cz = sz[widx];   // LDS broadcast reads
    }
    __syncthreads();
    for (int s = t; s < NPOINT; s += THREADS) {
        int id = sel[s];
        float X = sx[id], Y = sy[id], Z = sz[id];
        nxyz[(size_t)(b * NPOINT + s) * 3 + 0] = X;
        nxyz[(size_t)(b * NPOINT + s) * 3 + 1] = Y;
        nxyz[(size_t)(b * NPOINT + s) * 3 + 2] = Z;
        lxyz[(size_t)b * 3 * NPOINT + 0 * NPOINT + s] = X;
        lxyz[(size_t)b * 3 * NPOINT + 1 * NPOINT + s] = Y;
        lxyz[(size_t)b * 3 * NPOINT + 2 * NPOINT + s] = Z;
    }
}

// ---------------- SA1 per-point projection: p1[b,n,64] = [xyz,pts]·W1 + b1 ----------------
__global__ __launch_bounds__(256)
void project6_kernel(const float* __restrict__ xyz, const float* __restrict__ pts,
                     const float* __restrict__ W, const float* __restrict__ bias,
                     float* __restrict__ outp)
{
    int idx = blockIdx.x * 256 + threadIdx.x;     // (b, n, d), d fastest (64)
    int d = idx & 63;
    int n = (idx >> 6) & 4095;
    int b = idx >> 18;
    const float* xb = xyz + (size_t)b * 3 * 4096 + n;
    const float* pb = pts + (size_t)b * 3 * 4096 + n;
    float a0 = xb[0], a1 = xb[4096], a2 = xb[2 * 4096];
    float a3 = pb[0], a4 = pb[4096], a5 = pb[2 * 4096];
    float acc = bias[d];
    acc += a0 * W[d] + a1 * W[64 + d] + a2 * W[128 + d];
    acc += a3 * W[192 + d] + a4 * W[256 + d] + a5 * W[320 + d];
    outp[idx] = acc;
}

// ---------------- Ball query (one wave per ball) + center projection q ----------------
template<int NS>
__global__ __launch_bounds__(64)
void ballquery_kernel(const float* __restrict__ xyz, int bStride, int cStride, int nStride, int N,
                      const float* __restrict__ nxyz, int S, float r2,
                      int* __restrict__ gi,
                      const float* __restrict__ W, int D, float* __restrict__ q)
{
    int bs = blockIdx.x;
    int b = bs / S;
    int l = threadIdx.x;
    float cx = nxyz[(size_t)bs * 3 + 0], cy = nxyz[(size_t)bs * 3 + 1], cz = nxyz[(size_t)bs * 3 + 2];
    float s2 = cx * cx + cy * cy + cz * cz;
    const float* xb = xyz + (size_t)b * bStride;
    int cnt = 0;
    int first = N - 1;   // matches jnp clip behavior if the ball were empty
    int* go = gi + (size_t)bs * NS;
    for (int base = 0; base < N; base += 64) {
        int n = base + l;
        float x = xb[(size_t)0 * cStride + (size_t)n * nStride];
        float y = xb[(size_t)1 * cStride + (size_t)n * nStride];
        float z = xb[(size_t)2 * cStride + (size_t)n * nStride];
        float x2 = x * x + y * y + z * z;
        float dot = cx * x + cy * y + cz * z;
        float sqr = (s2 + x2) - 2.0f * dot;      // reference expansion form
        bool pass = (sqr <= r2);
        unsigned long long m = __ballot(pass);
        if (cnt == 0 && m) first = base + (__ffsll((unsigned long long)m) - 1);
        int pos = cnt + __popcll(m & ((1ull << l) - 1ull));
        if (pass && pos < NS) go[pos] = n;
        cnt += __popcll(m);
        if (cnt >= NS) break;
    }
    if (cnt < NS && l >= cnt && l < NS) go[l] = first;  // pad with first hit
    for (int d = l; d < D; d += 64)
        q[(size_t)bs * D + d] = cx * W[d] + cy * W[D + d] + cz * W[2 * D + d];
}

// ---------------- BN1 statistics over gathered layer-1 preacts ----------------
__global__ __launch_bounds__(256)
void stats_gather_kernel(const float* __restrict__ p, const float* __restrict__ q,
                         const int* __restrict__ gi, int S, int K, int N, int C,
                         float* __restrict__ slots)
{
    int R = 256 / C;
    int c = threadIdx.x % C;
    int r = threadIdx.x / C;
    int M = BATCH * S * K;
    float sum = 0.f, sq = 0.f;
    for (int j = blockIdx.x * R + r; j < M; j += gridDim.x * R) {
        int g = gi[j];
        int bs = j / K;
        int bb = bs / S;
        float v = p[(size_t)(bb * N + g) * C + c] - q[(size_t)bs * C + c];
        sum += v; sq += v * v;
    }
    __shared__ float red[2][4][128];
    red[0][r][c] = sum; red[1][r][c] = sq;
    __syncthreads();
    if (threadIdx.x < C) {
        float s0 = 0.f, s1 = 0.f;
        for (int i = 0; i < R; ++i) { s0 += red[0][i][threadIdx.x]; s1 += red[1][i][threadIdx.x]; }
        int slot = blockIdx.x & (SLOTS1 - 1);
        atomicAdd(&slots[(size_t)(slot * 2 + 0) * C + threadIdx.x], s0);
        atomicAdd(&slots[(size_t)(slot * 2 + 1) * C + threadIdx.x], s1);
    }
}

// ---------------- BN1 statistics over raw rows (SA3) ----------------
__global__ __launch_bounds__(256)
void stats_raw_kernel(const float* __restrict__ h, int M, int C, float* __restrict__ slots)
{
    int c = threadIdx.x;   // C == 256
    float sum = 0.f, sq = 0.f;
    for (int m = blockIdx.x; m < M; m += gridDim.x) {
        float v = h[(size_t)m * C + c];
        sum += v; sq += v * v;
    }
    int slot = blockIdx.x & (SLOTS1 - 1);
    atomicAdd(&slots[(size_t)(slot * 2 + 0) * C + c], sum);
    atomicAdd(&slots[(size_t)(slot * 2 + 1) * C + c], sq);
}

// ---------------- Tiled projection GEMM (SA2 p2, SA3 layer-1) ----------------
// out[b,n,:] = [xyz(b,n,0:3), feat(b,n,0:CF)]·W + bias   (K = CF+3, zero-padded panels)
template<int COUTB>
__global__ __launch_bounds__(512)
void proj_gemm_kernel(const float* __restrict__ xyzsrc, const float* __restrict__ featsrc,
                      int N, int CF,
                      const float* __restrict__ W, int coutFull,
                      const float* __restrict__ bias, float* __restrict__ outp)
{
    constexpr int BK = 32, BKP = 36, TK = 4, TC = 4, THREADS = 512, ROWS = 64;
    constexpr int C2G = COUTB / TC;
    static_assert(C2G * (ROWS / TK) == THREADS, "thread shape");
    __shared__ __attribute__((aligned(16))) float al[ROWS][BKP];
    __shared__ __attribute__((aligned(16))) float wl[COUTB][BKP];
    const int NCH = coutFull / COUTB;
    const int chunk = blockIdx.x % NCH;
    const int rb = blockIdx.x / NCH;
    const int m0 = rb * ROWS;
    const int c2_0 = chunk * COUTB;
    const int K = CF + 3;
    const int tid = threadIdx.x;
    const int c2g = tid % C2G, kt = tid / C2G;
    float acc[TK][TC];
#pragma unroll
    for (int i = 0; i < TK; ++i)
#pragma unroll
        for (int j = 0; j < TC; ++j) acc[i][j] = 0.f;
    const int npan = (K + BK - 1) / BK;
    for (int pan = 0; pan < npan; ++pan) {
        __syncthreads();
        const int cbase = pan * BK;
        for (int e = tid; e < ROWS * BK; e += THREADS) {
            int rl = e / BK, cl = e % BK;
            int c = cbase + cl;
            int m = m0 + rl;
            int bb = m / N, n = m % N;
            float v = 0.f;
            if (c < 3) v = xyzsrc[(size_t)(bb * N + n) * 3 + c];
            else if (c < K) v = featsrc[(size_t)(bb * N + n) * CF + (c - 3)];
            al[rl][cl] = v;
        }
        for (int e = tid; e < COUTB * BK; e += THREADS) {
            int c2 = e % COUTB, cl = e / COUTB;
            int c = cbase + cl;
            wl[c2][cl] = (c < K) ? W[(size_t)c * coutFull + c2_0 + c2] : 0.f;
        }
        __syncthreads();
#pragma unroll
        for (int cl = 0; cl < BK; cl += 4) {
            float4 av[TK], wv[TC];
#pragma unroll
            for (int i = 0; i < TK; ++i) av[i] = *(const float4*)&al[kt * TK + i][cl];
#pragma unroll
            for (int j = 0; j < TC; ++j) wv[j] = *(const float4*)&wl[c2g + j * C2G][cl];
#pragma unroll
            for (int i = 0; i < TK; ++i)
#pragma unroll
                for (int j = 0; j < TC; ++j)
                    acc[i][j] += av[i].x * wv[j].x + av[i].y * wv[j].y
                               + av[i].z * wv[j].z + av[i].w * wv[j].w;
        }
    }
#pragma unroll
    for (int j = 0; j < TC; ++j) {
        float bb_ = bias[c2_0 + c2g + j * C2G];
#pragma unroll
        for (int i = 0; i < TK; ++i) {
            int m = m0 + kt * TK + i;
            outp[(size_t)m * coutFull + c2_0 + c2g + j * C2G] = acc[i][j] + bb_;
        }
    }
}

// ---------------- Fused layer-2: gather -> BN1+ReLU -> GEMM -> max/min over k + BN2 stats ----
// gather mode (gi!=null): rows p[b*N + gi[bs*K+k]], minus q[bs]; identity mode: rows p[b*K+k].
// Emits per-(block-object, c2) max & min of preact (+bias) and slotted per-channel sum/sumsq.
template<int K, int CIN, int COUTB, int TK, int TC, int THREADS>
__global__ __launch_bounds__(THREADS)
void gather_gemm_kernel(const float* __restrict__ p, const float* __restrict__ q,
                        const int* __restrict__ gi, int S, int NCH, int N,
                        const float* __restrict__ st1, float m1count,
                        const float* __restrict__ g1, const float* __restrict__ be1,
                        const float* __restrict__ W2, int coutFull,
                        const float* __restrict__ b2,
                        float* __restrict__ st2,
                        float* __restrict__ mx, float* __restrict__ mn)
{
    constexpr int BK = 32, BKP = 36;
    constexpr int C2G = COUTB / TC;
    constexpr int KTG = K / TK;
    constexpr int NW = THREADS / 64;
    constexpr int KPW = 64 / C2G;
    static_assert(C2G * KTG == THREADS, "thread shape");
    __shared__ float ss_scale[CIN], ss_shift[CIN];
    __shared__ __attribute__((aligned(16))) float hl[K][BKP];
    __shared__ __attribute__((aligned(16))) float wl[COUTB][BKP];
    __shared__ float red[4][NW][COUTB];

    const int chunk = blockIdx.x % NCH;
    const int bs = blockIdx.x / NCH;
    const int b = bs / S;
    const int tid = threadIdx.x;
    const int c2_0 = chunk * COUTB;
    const int c2g = tid % C2G, kt = tid / C2G;
    const bool gather = (gi != nullptr);

    // finalize BN1 from slotted stats
    for (int c = tid; c < CIN; c += THREADS) {
        float s0 = 0.f, s1 = 0.f;
        for (int sl = 0; sl < SLOTS1; ++sl) {
            s0 += st1[(size_t)(sl * 2 + 0) * CIN + c];
            s1 += st1[(size_t)(sl * 2 + 1) * CIN + c];
        }
        float mean = s0 / m1count;
        float var = s1 / m1count - mean * mean;
        float inv = 1.0f / sqrtf(var + EPSB);
        float sc = g1[c] * inv;
        ss_scale[c] = sc;
        ss_shift[c] = be1[c] - sc * mean;
    }

    float acc[TK][TC];
#pragma unroll
    for (int i = 0; i < TK; ++i)
#pragma unroll
        for (int j = 0; j < TC; ++j) acc[i][j] = 0.f;

    for (int pan = 0; pan < CIN / BK; ++pan) {
        __syncthreads();   // also covers ss_* readiness on first pass
        const int cbase = pan * BK;
        for (int e = tid; e < K * BK; e += THREADS) {
            int k = e / BK, cl = e % BK;
            int c1 = cbase + cl;
            int row = gather ? (b * N + gi[(size_t)bs * K + k]) : (b * K + k);
            float v = p[(size_t)row * CIN + c1];
            if (q) v -= q[(size_t)bs * CIN + c1];
            v = fmaxf(ss_scale[c1] * v + ss_shift[c1], 0.f);
            hl[k][cl] = v;
        }
        for (int e = tid; e < COUTB * BK; e += THREADS) {
            int c2 = e % COUTB, cl = e / COUTB;
            wl[c2][cl] = W2[(size_t)(cbase + cl) * coutFull + c2_0 + c2];
        }
        __syncthreads();
#pragma unroll
        for (int cl = 0; cl < BK; cl += 4) {
            float4 av[TK], wv[TC];
#pragma unroll
            for (int i = 0; i < TK; ++i) av[i] = *(const float4*)&hl[kt * TK + i][cl];
#pragma unroll
            for (int j = 0; j < TC; ++j) wv[j] = *(const float4*)&wl[c2g + j * C2G][cl];
#pragma unroll
            for (int i = 0; i < TK; ++i)
#pragma unroll
                for (int j = 0; j < TC; ++j)
                    acc[i][j] += av[i].x * wv[j].x + av[i].y * wv[j].y
                               + av[i].z * wv[j].z + av[i].w * wv[j].w;
        }
    }

    // per-thread partials over its TK samples (preact includes bias)
    float psum[TC], psq[TC], pmx[TC], pmn[TC];
#pragma unroll
    for (int j = 0; j < TC; ++j) {
        float bb_ = b2[c2_0 + c2g + j * C2G];
        float s = 0.f, ss = 0.f, mx_ = -3.4e38f, mn_ = 3.4e38f;
#pragma unroll
        for (int i = 0; i < TK; ++i) {
            float v = acc[i][j] + bb_;
            s += v; ss += v * v; mx_ = fmaxf(mx_, v); mn_ = fminf(mn_, v);
        }
        psum[j] = s; psq[j] = ss; pmx[j] = mx_; pmn[j] = mn_;
    }
    // shuffle-reduce across kt groups within each wave
#pragma unroll
    for (int off = C2G; off < 64; off <<= 1) {
#pragma unroll
        for (int j = 0; j < TC; ++j) {
            psum[j] += __shfl_down(psum[j], off);
            psq[j]  += __shfl_down(psq[j], off);
            pmx[j] = fmaxf(pmx[j], __shfl_down(pmx[j], off));
            pmn[j] = fminf(pmn[j], __shfl_down(pmn[j], off));
        }
    }
    if ((kt % KPW) == 0) {
        int wrow = kt / KPW;
#pragma unroll
        for (int j = 0; j < TC; ++j) {
            int c2 = c2g + j * C2G;
            red[0][wrow][c2] = psum[j];
            red[1][wrow][c2] = psq[j];
            red[2][wrow][c2] = pmx[j];
            red[3][wrow][c2] = pmn[j];
        }
    }
    __syncthreads();
    if (tid < COUTB) {
        float s = 0.f, ss = 0.f, mxv = -3.4e38f, mnv = 3.4e38f;
        for (int w = 0; w < NW; ++w) {
            s += red[0][w][tid]; ss += red[1][w][tid];
            mxv = fmaxf(mxv, red[2][w][tid]);
            mnv = fminf(mnv, red[3][w][tid]);
        }
        int slot = blockIdx.x & (SLOTS2 - 1);
        atomicAdd(&st2[(size_t)(slot * 2 + 0) * coutFull + c2_0 + tid], s);
        atomicAdd(&st2[(size_t)(slot * 2 + 1) * coutFull + c2_0 + tid], ss);
        mx[(size_t)bs * coutFull + c2_0 + tid] = mxv;
        mn[(size_t)bs * coutFull + c2_0 + tid] = mnv;
    }
}

// ---------------- Finalize BN2, apply to max/min, ReLU, write feat + transposed out --------
__global__ __launch_bounds__(256)
void apply_kernel(const float* __restrict__ st2, int C, float m2count,
                  const float* __restrict__ g2, const float* __restrict__ be2,
                  const float* __restrict__ mx, const float* __restrict__ mn,
                  int S, float* __restrict__ feat, float* __restrict__ outT,
                  int total, float* __restrict__ zero48)
{
    __shared__ float sc[512], sh[512];
    for (int c = threadIdx.x; c < C; c += 256) {
        float s0 = 0.f, s1 = 0.f;
        for (int sl = 0; sl < SLOTS2; ++sl) {
            s0 += st2[(size_t)(sl * 2 + 0) * C + c];
            s1 += st2[(size_t)(sl * 2 + 1) * C + c];
        }
        float mean = s0 / m2count;
        float var = s1 / m2count - mean * mean;
        float inv = 1.0f / sqrtf(var + EPSB);
        float scl = g2[c] * inv;
        sc[c] = scl; sh[c] = be2[c] - scl * mean;
    }
    __syncthreads();
    if (zero48 && blockIdx.x == 0 && threadIdx.x < 48) zero48[threadIdx.x] = 0.f;
    for (int e = blockIdx.x * 256 + threadIdx.x; e < total; e += gridDim.x * 256) {
        int c = e % C;
        int s = (e / C) % S;
        int b = e / (C * S);
        float scl = sc[c];
        float v = (scl >= 0.f) ? mx[e] : mn[e];   // maxpool commutes: sign picks extremum
        float y = fmaxf(scl * v + sh[c], 0.f);
        if (feat) feat[e] = y;
        outT[((size_t)b * C + c) * S + s] = y;
    }
}

extern "C" void kernel_launch(void* const* d_in, const int* in_sizes, int n_in,
                              void* d_out, int out_size, void* d_ws, size_t ws_size,
                              hipStream_t stream)
{
    (void)in_sizes; (void)n_in; (void)out_size; (void)ws_size;
    const float* l0_xyz = (const float*)d_in[0];
    const float* l0_pts = (const float*)d_in[1];
    const float* w11 = (const float*)d_in[2];  const float* b11 = (const float*)d_in[3];
    const float* g11 = (const float*)d_in[4];  const float* be11 = (const float*)d_in[5];
    const float* w12 = (const float*)d_in[6];  const float* b12 = (const float*)d_in[7];
    const float* g12 = (const float*)d_in[8];  const float* be12 = (const float*)d_in[9];
    const float* w21 = (const float*)d_in[10]; const float* b21 = (const float*)d_in[11];
    const float* g21 = (const float*)d_in[12]; const float* be21 = (const float*)d_in[13];
    const float* w22 = (const float*)d_in[14]; const float* b22 = (const float*)d_in[15];
    const float* g22 = (const float*)d_in[16]; const float* be22 = (const float*)d_in[17];
    const float* w31 = (const float*)d_in[18]; const float* b31 = (const float*)d_in[19];
    const float* g31 = (const float*)d_in[20]; const float* be31 = (const float*)d_in[21];
    const float* w32 = (const float*)d_in[22]; const float* b32 = (const float*)d_in[23];
    const float* g32 = (const float*)d_in[24]; const float* be32 = (const float*)d_in[25];

    float* out = (float*)d_out;
    float* o_l1xyz = out;                 // (16,3,256)
    float* o_l1pts = out + 12288;         // (16,128,256)
    float* o_l2xyz = out + 536576;        // (16,3,128)
    float* o_l2pts = out + 542720;        // (16,256,128)
    float* o_l3xyz = out + 1067008;       // (16,3,1)
    float* o_x     = out + 1067056;       // (16,512)

    char* ws = (char*)d_ws;
    size_t off = 0;
    auto alloc = [&](size_t elems) {
        void* r = ws + off;
        off += ((elems * 4 + 255) & ~(size_t)255);
        return r;
    };
    float* nxyz1 = (float*)alloc(12288);
    float* nxyz2 = (float*)alloc(6144);
    int*   gi1   = (int*)alloc(131072);
    int*   gi2   = (int*)alloc(131072);
    float* p1    = (float*)alloc(4194304);
    float* q1    = (float*)alloc(262144);
    float* feat1 = (float*)alloc(524288);
    float* mx1   = (float*)alloc(524288);
    float* mn1   = (float*)alloc(524288);
    float* p2    = (float*)alloc(524288);
    float* q2    = (float*)alloc(262144);
    float* feat2 = (float*)alloc(524288);
    float* mx2   = (float*)alloc(524288);
    float* mn2   = (float*)alloc(524288);
    float* h31   = (float*)alloc(524288);
    float* mx3   = (float*)alloc(8192);
    float* mn3   = (float*)alloc(8192);
    float* stats = (float*)alloc(129024);
    float* st1a = stats;                 // 16*2*64
    float* st2a = st1a + 2048;           // 64*2*128
    float* st1b = st2a + 16384;          // 16*2*128
    float* st2b = st1b + 4096;           // 64*2*256
    float* st3a = st2b + 32768;          // 16*2*256
    float* st3b = st3a + 8192;           // 64*2*512

    hipMemsetAsync(stats, 0, 129024 * sizeof(float), stream);

    // ---- SA1 ----
    fps_kernel<4096, 256, 512><<<16, 512, 0, stream>>>(l0_xyz, 3 * 4096, 4096, 1, nxyz1, o_l1xyz);
    project6_kernel<<<16384, 256, 0, stream>>>(l0_xyz, l0_pts, w11, b11, p1);
    ballquery_kernel<32><<<4096, 64, 0, stream>>>(l0_xyz, 3 * 4096, 4096, 1, 4096,
                                                  nxyz1, 256, 0.04f, gi1, w11, 64, q1);
    stats_gather_kernel<<<256, 256, 0, stream>>>(p1, q1, gi1, 256, 32, 4096, 64, st1a);
    gather_gemm_kernel<32, 64, 128, 4, 4, 256><<<4096, 256, 0, stream>>>(
        p1, q1, gi1, 256, 1, 4096, st1a, 131072.0f, g11, be11, w12, 128, b12, st2a, mx1, mn1);
    apply_kernel<<<128, 256, 0, stream>>>(st2a, 128, 131072.0f, g12, be12, mx1, mn1,
                                          256, feat1, o_l1pts, 524288, nullptr);

    // ---- SA2 ----
    fps_kernel<256, 128, 64><<<16, 64, 0, stream>>>(nxyz1, 768, 1, 3, nxyz2, o_l2xyz);
    proj_gemm_kernel<128><<<64, 512, 0, stream>>>(nxyz1, feat1, 256, 128, w21, 128, b21, p2);
    ballquery_kernel<64><<<2048, 64, 0, stream>>>(nxyz1, 768, 1, 3, 256,
                                                  nxyz2, 128, 0.0625f, gi2, w21, 128, q2);
    stats_gather_kernel<<<256, 256, 0, stream>>>(p2, q2, gi2, 128, 64, 256, 128, st1b);
    gather_gemm_kernel<64, 128, 128, 4, 4, 512><<<4096, 512, 0, stream>>>(
        p2, q2, gi2, 128, 2, 256, st1b, 131072.0f, g21, be21, w22, 256, b22, st2b, mx2, mn2);
    apply_kernel<<<128, 256, 0, stream>>>(st2b, 256, 131072.0f, g22, be22, mx2, mn2,
                                          128, feat2, o_l2pts, 524288, nullptr);

    // ---- SA3 (group_all) ----
    proj_gemm_kernel<128><<<64, 512, 0, stream>>>(nxyz2, feat2, 128, 256, w31, 256, b31, h31);
    stats_raw_kernel<<<128, 256, 0, stream>>>(h31, 2048, 256, st3a);
    gather_gemm_kernel<128, 256, 64, 4, 4, 512><<<128, 512, 0, stream>>>(
        h31, nullptr, nullptr, 1, 8, 0, st3a, 2048.0f, g31, be31, w32, 512, b32, st3b, mx3, mn3);
    apply_kernel<<<32, 256, 0, stream>>>(st3b, 512, 2048.0f, g32, be32, mx3, mn3,
                                         1, nullptr, o_x, 8192, o_l3xyz);
}

// Round 3
// 828.225 us; speedup vs baseline: 1.7032x; 1.3265x over previous
//
#include <hip/hip_runtime.h>
#include <cstddef>

// PointNet++ set-abstraction pipeline (B=16, N=4096, HC=64), fp32 front-end.
// R3: layer-2 GEMMs (gather->BN1+ReLU->GEMM->pool-extrema+BN2-stats) moved to
// bf16 MFMA (mfma_f32_16x16x32_bf16, fp32 accumulate). Weights pre-transposed
// to bf16 w2t[n][k]; BN1 scale/shift pre-finalized in a tiny kernel.

#define EPSB 1e-5f
constexpr int SLOTS1 = 16;
constexpr int SLOTS2 = 64;
constexpr int BATCH = 16;

static __device__ __forceinline__ unsigned long long umax64(unsigned long long a,
                                                            unsigned long long b)
{
    return a > b ? a : b;
}

static __device__ __forceinline__ unsigned pack_bf16x2(float a, float b)
{
    unsigned ua = __float_as_uint(a), ub = __float_as_uint(b);
    ua += 0x7fffu + ((ua >> 16) & 1u);
    ub += 0x7fffu + ((ub >> 16) & 1u);
    return (ua >> 16) | (ub & 0xffff0000u);
}

// ---------------- FPS (R2 design: packed u64 argmax key, LDS coord table) ------------
template<int N, int NPOINT, int THREADS>
__global__ __launch_bounds__(THREADS)
void fps_kernel(const float* __restrict__ xyz, int bStride, int cStride, int nStride,
                float* __restrict__ nxyz, float* __restrict__ lxyz)
{
    constexpr int PT = N / THREADS;
    constexpr int NW = THREADS / 64;
    const int b = blockIdx.x, t = threadIdx.x;
    const float* xb = xyz + (size_t)b * bStride;

    __shared__ float sx[N], sy[N], sz[N];
    __shared__ unsigned long long red[2][NW > 1 ? NW : 1];
    __shared__ int sel[NPOINT];

    float px[PT], py[PT], pz[PT], dist[PT];
#pragma unroll
    for (int i = 0; i < PT; ++i) {
        int p = t + i * THREADS;
        px[i] = xb[(size_t)0 * cStride + (size_t)p * nStride];
        py[i] = xb[(size_t)1 * cStride + (size_t)p * nStride];
        pz[i] = xb[(size_t)2 * cStride + (size_t)p * nStride];
        sx[p] = px[i]; sy[p] = py[i]; sz[p] = pz[i];
        dist[i] = 1e10f;
    }
    if (t == 0) sel[0] = 0;
    __syncthreads();

    float cx = sx[0], cy = sy[0], cz = sz[0];
    for (int it = 1; it < NPOINT; ++it) {
        unsigned long long best = 0ull;
#pragma unroll
        for (int i = 0; i < PT; ++i) {
            float dx = px[i] - cx, dy = py[i] - cy, dz = pz[i] - cz;
            float d = __builtin_fmaf(dx, dx, __builtin_fmaf(dy, dy, dz * dz));
            float nd = fminf(dist[i], d);
            dist[i] = nd;
            unsigned long long k =
                ((unsigned long long)__float_as_uint(nd) << 32) |
                (unsigned int)(~(t + i * THREADS));
            best = umax64(best, k);
        }
        int widx;
        if constexpr (NW > 1) {
#pragma unroll
            for (int off = 32; off > 0; off >>= 1)
                best = umax64(best, __shfl_down(best, off));
            const int pb = it & 1;
            if ((t & 63) == 0) red[pb][t >> 6] = best;
            __syncthreads();
            unsigned long long m = red[pb][0];
#pragma unroll
            for (int w = 1; w < NW; ++w) m = umax64(m, red[pb][w]);
            widx = (int)(~(unsigned int)m);
        } else {
#pragma unroll
            for (int off = 1; off < 64; off <<= 1)
                best = umax64(best, __shfl_xor(best, off));
            widx = (int)(~(unsigned int)best);
        }
        if (t == 0) sel[it] = widx;
        cx = sx[widx]; cy = sy[widx]; cz = sz[widx];
    }
    __syncthreads();
    for (int s = t; s < NPOINT; s += THREADS) {
        int id = sel[s];
        float X = sx[id], Y = sy[id], Z = sz[id];
        nxyz[(size_t)(b * NPOINT + s) * 3 + 0] = X;
        nxyz[(size_t)(b * NPOINT + s) * 3 + 1] = Y;
        nxyz[(size_t)(b * NPOINT + s) * 3 + 2] = Z;
        lxyz[(size_t)b * 3 * NPOINT + 0 * NPOINT + s] = X;
        lxyz[(size_t)b * 3 * NPOINT + 1 * NPOINT + s] = Y;
        lxyz[(size_t)b * 3 * NPOINT + 2 * NPOINT + s] = Z;
    }
}

// ---------------- SA1 per-point projection ----------------
__global__ __launch_bounds__(256)
void project6_kernel(const float* __restrict__ xyz, const float* __restrict__ pts,
                     const float* __restrict__ W, const float* __restrict__ bias,
                     float* __restrict__ outp)
{
    int idx = blockIdx.x * 256 + threadIdx.x;
    int d = idx & 63;
    int n = (idx >> 6) & 4095;
    int b = idx >> 18;
    const float* xb = xyz + (size_t)b * 3 * 4096 + n;
    const float* pb = pts + (size_t)b * 3 * 4096 + n;
    float a0 = xb[0], a1 = xb[4096], a2 = xb[2 * 4096];
    float a3 = pb[0], a4 = pb[4096], a5 = pb[2 * 4096];
    float acc = bias[d];
    acc += a0 * W[d] + a1 * W[64 + d] + a2 * W[128 + d];
    acc += a3 * W[192 + d] + a4 * W[256 + d] + a5 * W[320 + d];
    outp[idx] = acc;
}

// ---------------- Ball query (one wave per ball) + center projection q ----------------
template<int NS>
__global__ __launch_bounds__(64)
void ballquery_kernel(const float* __restrict__ xyz, int bStride, int cStride, int nStride, int N,
                      const float* __restrict__ nxyz, int S, float r2,
                      int* __restrict__ gi,
                      const float* __restrict__ W, int D, float* __restrict__ q)
{
    int bs = blockIdx.x;
    int b = bs / S;
    int l = threadIdx.x;
    float cx = nxyz[(size_t)bs * 3 + 0], cy = nxyz[(size_t)bs * 3 + 1], cz = nxyz[(size_t)bs * 3 + 2];
    float s2 = cx * cx + cy * cy + cz * cz;
    const float* xb = xyz + (size_t)b * bStride;
    int cnt = 0;
    int first = N - 1;
    int* go = gi + (size_t)bs * NS;
    for (int base = 0; base < N; base += 64) {
        int n = base + l;
        float x = xb[(size_t)0 * cStride + (size_t)n * nStride];
        float y = xb[(size_t)1 * cStride + (size_t)n * nStride];
        float z = xb[(size_t)2 * cStride + (size_t)n * nStride];
        float x2 = x * x + y * y + z * z;
        float dot = cx * x + cy * y + cz * z;
        float sqr = (s2 + x2) - 2.0f * dot;
        bool pass = (sqr <= r2);
        unsigned long long m = __ballot(pass);
        if (cnt == 0 && m) first = base + (__ffsll((unsigned long long)m) - 1);
        int pos = cnt + __popcll(m & ((1ull << l) - 1ull));
        if (pass && pos < NS) go[pos] = n;
        cnt += __popcll(m);
        if (cnt >= NS) break;
    }
    if (cnt < NS && l >= cnt && l < NS) go[l] = first;
    for (int d = l; d < D; d += 64)
        q[(size_t)bs * D + d] = cx * W[d] + cy * W[D + d] + cz * W[2 * D + d];
}

// ---------------- BN1 statistics over gathered layer-1 preacts ----------------
__global__ __launch_bounds__(256)
void stats_gather_kernel(const float* __restrict__ p, const float* __restrict__ q,
                         const int* __restrict__ gi, int S, int K, int N, int C,
                         float* __restrict__ slots)
{
    int R = 256 / C;
    int c = threadIdx.x % C;
    int r = threadIdx.x / C;
    int M = BATCH * S * K;
    float sum = 0.f, sq = 0.f;
    for (int j = blockIdx.x * R + r; j < M; j += gridDim.x * R) {
        int g = gi[j];
        int bs = j / K;
        int bb = bs / S;
        float v = p[(size_t)(bb * N + g) * C + c] - q[(size_t)bs * C + c];
        sum += v; sq += v * v;
    }
    __shared__ float red[2][4][128];
    red[0][r][c] = sum; red[1][r][c] = sq;
    __syncthreads();
    if (threadIdx.x < C) {
        float s0 = 0.f, s1 = 0.f;
        for (int i = 0; i < R; ++i) { s0 += red[0][i][threadIdx.x]; s1 += red[1][i][threadIdx.x]; }
        int slot = blockIdx.x & (SLOTS1 - 1);
        atomicAdd(&slots[(size_t)(slot * 2 + 0) * C + threadIdx.x], s0);
        atomicAdd(&slots[(size_t)(slot * 2 + 1) * C + threadIdx.x], s1);
    }
}

// ---------------- BN1 statistics over raw rows (SA3) ----------------
__global__ __launch_bounds__(256)
void stats_raw_kernel(const float* __restrict__ h, int M, int C, float* __restrict__ slots)
{
    int c = threadIdx.x;   // C == 256
    float sum = 0.f, sq = 0.f;
    for (int m = blockIdx.x; m < M; m += gridDim.x) {
        float v = h[(size_t)m * C + c];
        sum += v; sq += v * v;
    }
    int slot = blockIdx.x & (SLOTS1 - 1);
    atomicAdd(&slots[(size_t)(slot * 2 + 0) * C + c], sum);
    atomicAdd(&slots[(size_t)(slot * 2 + 1) * C + c], sq);
}

// ---------------- Finalize BN1 -> scale/shift arrays (once) ----------------
__global__ __launch_bounds__(256)
void bnfin_kernel(const float* __restrict__ st, int C, float cnt,
                  const float* __restrict__ g, const float* __restrict__ be,
                  float* __restrict__ sc, float* __restrict__ sh)
{
    int c = blockIdx.x * 256 + threadIdx.x;
    if (c >= C) return;
    float s0 = 0.f, s1 = 0.f;
    for (int sl = 0; sl < SLOTS1; ++sl) {
        s0 += st[(size_t)(sl * 2 + 0) * C + c];
        s1 += st[(size_t)(sl * 2 + 1) * C + c];
    }
    float mean = s0 / cnt;
    float var = s1 / cnt - mean * mean;
    float inv = 1.0f / sqrtf(var + EPSB);
    float s = g[c] * inv;
    sc[c] = s;
    sh[c] = be[c] - s * mean;
}

// ---------------- Weight transpose + bf16 convert: w2t[n][k] = bf16(W[k][n]) -------
__global__ __launch_bounds__(256)
void w2t_kernel(const float* __restrict__ W, int K, int Ncout, unsigned short* __restrict__ out)
{
    int i = blockIdx.x * 256 + threadIdx.x;
    if (i >= K * Ncout) return;
    int k = i / Ncout, n = i % Ncout;
    unsigned u = __float_as_uint(W[i]);
    u += 0x7fffu + ((u >> 16) & 1u);
    out[(size_t)n * K + k] = (unsigned short)(u >> 16);
}

// ---------------- Tiled projection GEMM (SA2 p2, SA3 layer-1), fp32 ----------------
template<int COUTB>
__global__ __launch_bounds__(512)
void proj_gemm_kernel(const float* __restrict__ xyzsrc, const float* __restrict__ featsrc,
                      int N, int CF,
                      const float* __restrict__ W, int coutFull,
                      const float* __restrict__ bias, float* __restrict__ outp)
{
    constexpr int BK = 32, BKP = 36, TK = 4, TC = 4, THREADS = 512, ROWS = 64;
    constexpr int C2G = COUTB / TC;
    static_assert(C2G * (ROWS / TK) == THREADS, "thread shape");
    __shared__ __attribute__((aligned(16))) float al[ROWS][BKP];
    __shared__ __attribute__((aligned(16))) float wl[COUTB][BKP];
    const int NCH = coutFull / COUTB;
    const int chunk = blockIdx.x % NCH;
    const int rb = blockIdx.x / NCH;
    const int m0 = rb * ROWS;
    const int c2_0 = chunk * COUTB;
    const int K = CF + 3;
    const int tid = threadIdx.x;
    const int c2g = tid % C2G, kt = tid / C2G;
    float acc[TK][TC];
#pragma unroll
    for (int i = 0; i < TK; ++i)
#pragma unroll
        for (int j = 0; j < TC; ++j) acc[i][j] = 0.f;
    const int npan = (K + BK - 1) / BK;
    for (int pan = 0; pan < npan; ++pan) {
        __syncthreads();
        const int cbase = pan * BK;
        for (int e = tid; e < ROWS * BK; e += THREADS) {
            int rl = e / BK, cl = e % BK;
            int c = cbase + cl;
            int m = m0 + rl;
            int bb = m / N, n = m % N;
            float v = 0.f;
            if (c < 3) v = xyzsrc[(size_t)(bb * N + n) * 3 + c];
            else if (c < K) v = featsrc[(size_t)(bb * N + n) * CF + (c - 3)];
            al[rl][cl] = v;
        }
        for (int e = tid; e < COUTB * BK; e += THREADS) {
            int c2 = e % COUTB, cl = e / COUTB;
            int c = cbase + cl;
            wl[c2][cl] = (c < K) ? W[(size_t)c * coutFull + c2_0 + c2] : 0.f;
        }
        __syncthreads();
#pragma unroll
        for (int cl = 0; cl < BK; cl += 4) {
            float4 av[TK], wv[TC];
#pragma unroll
            for (int i = 0; i < TK; ++i) av[i] = *(const float4*)&al[kt * TK + i][cl];
#pragma unroll
            for (int j = 0; j < TC; ++j) wv[j] = *(const float4*)&wl[c2g + j * C2G][cl];
#pragma unroll
            for (int i = 0; i < TK; ++i)
#pragma unroll
                for (int j = 0; j < TC; ++j)
                    acc[i][j] += av[i].x * wv[j].x + av[i].y * wv[j].y
                               + av[i].z * wv[j].z + av[i].w * wv[j].w;
        }
    }
#pragma unroll
    for (int j = 0; j < TC; ++j) {
        float bb_ = bias[c2_0 + c2g + j * C2G];
#pragma unroll
        for (int i = 0; i < TK; ++i) {
            int m = m0 + kt * TK + i;
            outp[(size_t)m * coutFull + c2_0 + c2g + j * C2G] = acc[i][j] + bb_;
        }
    }
}

// ---------------- MFMA layer-2: gather -> BN1+ReLU(bf16) -> MFMA GEMM -> extrema+stats ----
// One ball (or object chunk) per block, 512 threads = 8 waves.
// A: hl[KS][CIN+8] bf16 in LDS (A-frag: m=lane&15, k=quad*8+j).
// B: w2t[n][k] bf16 from global (L1/L2-hot), 16B per fragment load.
// D: col=lane&15, row=quad*4+reg; quad-reduce via shfl_xor(16,32).
template<int KS, int CIN, int COUTB>
__global__ __launch_bounds__(512)
void mfma_gemm_kernel(const float* __restrict__ p, const float* __restrict__ q,
                      const int* __restrict__ gi, int S, int NCH, int N,
                      const float* __restrict__ bnsc, const float* __restrict__ bnsh,
                      const unsigned short* __restrict__ w2t, int coutFull,
                      const float* __restrict__ b2,
                      float* __restrict__ st2,
                      float* __restrict__ mx, float* __restrict__ mn)
{
    constexpr int MT = KS / 16;        // m-tiles (waves along m)
    constexpr int NSL = 8 / MT;        // n-slices (waves along n)
    constexpr int SLW = COUTB / NSL;   // cols per wave slice
    constexpr int TPW = SLW / 16;      // 16-col tiles per wave
    constexpr int KST = CIN / 32;      // k-steps
    constexpr int LDA = CIN + 8;       // bf16 row stride (2-way-free banks, 16B-aligned)
    typedef __attribute__((ext_vector_type(8))) short bf16x8;
    typedef __attribute__((ext_vector_type(4))) float f32x4;

    __shared__ __attribute__((aligned(16))) unsigned short hl[KS][LDA];
    __shared__ float red[4][8][SLW];

    const int chunk = blockIdx.x % NCH;
    const int bs = blockIdx.x / NCH;
    const int b = bs / S;
    const int tid = threadIdx.x;
    const int c2_0 = chunk * COUTB;
    const int w = tid >> 6, lane = tid & 63;
    const int mt = w % MT, ns = w / MT;
    const int lrow = lane & 15, quad = lane >> 4;

    // ---- stage gathered rows -> BN1+ReLU -> bf16 LDS ----
    constexpr int ITER = KS * CIN / (512 * 4);
    const int gbase = bs * KS;
#pragma unroll
    for (int it = 0; it < ITER; ++it) {
        int e = (it * 512 + tid) * 4;
        int k = e / CIN, c = e % CIN;
        int row = gi ? (b * N + gi[gbase + k]) : (b * KS + k);
        float4 v = *(const float4*)&p[(size_t)row * CIN + c];
        if (q) {
            float4 qq = *(const float4*)&q[(size_t)bs * CIN + c];
            v.x -= qq.x; v.y -= qq.y; v.z -= qq.z; v.w -= qq.w;
        }
        float4 sc = *(const float4*)&bnsc[c];
        float4 sh = *(const float4*)&bnsh[c];
        v.x = fmaxf(__builtin_fmaf(sc.x, v.x, sh.x), 0.f);
        v.y = fmaxf(__builtin_fmaf(sc.y, v.y, sh.y), 0.f);
        v.z = fmaxf(__builtin_fmaf(sc.z, v.z, sh.z), 0.f);
        v.w = fmaxf(__builtin_fmaf(sc.w, v.w, sh.w), 0.f);
        uint2 pk;
        pk.x = pack_bf16x2(v.x, v.y);
        pk.y = pack_bf16x2(v.z, v.w);
        *(uint2*)&hl[k][c] = pk;
    }
    __syncthreads();

    // ---- MFMA main loop ----
    f32x4 acc[TPW];
#pragma unroll
    for (int t = 0; t < TPW; ++t) acc[t] = (f32x4){0.f, 0.f, 0.f, 0.f};

    const int nbase = c2_0 + ns * SLW + lrow;
#pragma unroll
    for (int ks = 0; ks < KST; ++ks) {
        bf16x8 a = *(const bf16x8*)&hl[mt * 16 + lrow][ks * 32 + quad * 8];
#pragma unroll
        for (int t = 0; t < TPW; ++t) {
            bf16x8 bfr = *(const bf16x8*)&w2t[(size_t)(nbase + t * 16) * CIN + ks * 32 + quad * 8];
            acc[t] = __builtin_amdgcn_mfma_f32_16x16x32_bf16(a, bfr, acc[t], 0, 0, 0);
        }
    }

    // ---- epilogue: bias, per-wave quad-reduce, LDS, cross-mt combine ----
#pragma unroll
    for (int t = 0; t < TPW; ++t) {
        float bias = b2[nbase + t * 16];
        float s = 0.f, sq = 0.f, amx = -3.4e38f, amn = 3.4e38f;
#pragma unroll
        for (int r = 0; r < 4; ++r) {
            float v = acc[t][r] + bias;
            s += v; sq += v * v;
            amx = fmaxf(amx, v); amn = fminf(amn, v);
        }
#pragma unroll
        for (int off = 16; off < 64; off <<= 1) {
            s += __shfl_xor(s, off);
            sq += __shfl_xor(sq, off);
            amx = fmaxf(amx, __shfl_xor(amx, off));
            amn = fminf(amn, __shfl_xor(amn, off));
        }
        if (quad == 0) {
            int lc = t * 16 + lrow;
            red[0][w][lc] = s; red[1][w][lc] = sq;
            red[2][w][lc] = amx; red[3][w][lc] = amn;
        }
    }
    __syncthreads();
    for (int c = tid; c < COUTB; c += 512) {
        int ns2 = c / SLW, lc = c % SLW;
        float s = 0.f, sq = 0.f, amx = -3.4e38f, amn = 3.4e38f;
#pragma unroll
        for (int m2 = 0; m2 < MT; ++m2) {
            int w2 = ns2 * MT + m2;
            s += red[0][w2][lc]; sq += red[1][w2][lc];
            amx = fmaxf(amx, red[2][w2][lc]);
            amn = fminf(amn, red[3][w2][lc]);
        }
        int slot = blockIdx.x & (SLOTS2 - 1);
        atomicAdd(&st2[(size_t)(slot * 2 + 0) * coutFull + c2_0 + c], s);
        atomicAdd(&st2[(size_t)(slot * 2 + 1) * coutFull + c2_0 + c], sq);
        mx[(size_t)bs * coutFull + c2_0 + c] = amx;
        mn[(size_t)bs * coutFull + c2_0 + c] = amn;
    }
}

// ---------------- Finalize BN2, apply to max/min, ReLU, write feat + transposed out --------
__global__ __launch_bounds__(256)
void apply_kernel(const float* __restrict__ st2, int C, float m2count,
                  const float* __restrict__ g2, const float* __restrict__ be2,
                  const float* __restrict__ mx, const float* __restrict__ mn,
                  int S, float* __restrict__ feat, float* __restrict__ outT,
                  int total, float* __restrict__ zero48)
{
    __shared__ float sc[512], sh[512];
    for (int c = threadIdx.x; c < C; c += 256) {
        float s0 = 0.f, s1 = 0.f;
        for (int sl = 0; sl < SLOTS2; ++sl) {
            s0 += st2[(size_t)(sl * 2 + 0) * C + c];
            s1 += st2[(size_t)(sl * 2 + 1) * C + c];
        }
        float mean = s0 / m2count;
        float var = s1 / m2count - mean * mean;
        float inv = 1.0f / sqrtf(var + EPSB);
        float scl = g2[c] * inv;
        sc[c] = scl; sh[c] = be2[c] - scl * mean;
    }
    __syncthreads();
    if (zero48 && blockIdx.x == 0 && threadIdx.x < 48) zero48[threadIdx.x] = 0.f;
    for (int e = blockIdx.x * 256 + threadIdx.x; e < total; e += gridDim.x * 256) {
        int c = e % C;
        int s = (e / C) % S;
        int b = e / (C * S);
        float scl = sc[c];
        float v = (scl >= 0.f) ? mx[e] : mn[e];
        float y = fmaxf(scl * v + sh[c], 0.f);
        if (feat) feat[e] = y;
        outT[((size_t)b * C + c) * S + s] = y;
    }
}

extern "C" void kernel_launch(void* const* d_in, const int* in_sizes, int n_in,
                              void* d_out, int out_size, void* d_ws, size_t ws_size,
                              hipStream_t stream)
{
    (void)in_sizes; (void)n_in; (void)out_size; (void)ws_size;
    const float* l0_xyz = (const float*)d_in[0];
    const float* l0_pts = (const float*)d_in[1];
    const float* w11 = (const float*)d_in[2];  const float* b11 = (const float*)d_in[3];
    const float* g11 = (const float*)d_in[4];  const float* be11 = (const float*)d_in[5];
    const float* w12 = (const float*)d_in[6];  const float* b12 = (const float*)d_in[7];
    const float* g12 = (const float*)d_in[8];  const float* be12 = (const float*)d_in[9];
    const float* w21 = (const float*)d_in[10]; const float* b21 = (const float*)d_in[11];
    const float* g21 = (const float*)d_in[12]; const float* be21 = (const float*)d_in[13];
    const float* w22 = (const float*)d_in[14]; const float* b22 = (const float*)d_in[15];
    const float* g22 = (const float*)d_in[16]; const float* be22 = (const float*)d_in[17];
    const float* w31 = (const float*)d_in[18]; const float* b31 = (const float*)d_in[19];
    const float* g31 = (const float*)d_in[20]; const float* be31 = (const float*)d_in[21];
    const float* w32 = (const float*)d_in[22]; const float* b32 = (const float*)d_in[23];
    const float* g32 = (const float*)d_in[24]; const float* be32 = (const float*)d_in[25];

    float* out = (float*)d_out;
    float* o_l1xyz = out;                 // (16,3,256)
    float* o_l1pts = out + 12288;         // (16,128,256)
    float* o_l2xyz = out + 536576;        // (16,3,128)
    float* o_l2pts = out + 542720;        // (16,256,128)
    float* o_l3xyz = out + 1067008;       // (16,3,1)
    float* o_x     = out + 1067056;       // (16,512)

    char* ws = (char*)d_ws;
    size_t off = 0;
    auto alloc = [&](size_t bytes) {
        void* r = ws + off;
        off += ((bytes + 255) & ~(size_t)255);
        return r;
    };
    float* nxyz1 = (float*)alloc(12288 * 4);
    float* nxyz2 = (float*)alloc(6144 * 4);
    int*   gi1   = (int*)alloc(131072 * 4);
    int*   gi2   = (int*)alloc(131072 * 4);
    float* p1    = (float*)alloc(4194304 * 4);
    float* q1    = (float*)alloc(262144 * 4);
    float* feat1 = (float*)alloc(524288 * 4);
    float* mx1   = (float*)alloc(524288 * 4);
    float* mn1   = (float*)alloc(524288 * 4);
    float* p2    = (float*)alloc(524288 * 4);
    float* q2    = (float*)alloc(262144 * 4);
    float* feat2 = (float*)alloc(524288 * 4);
    float* mx2   = (float*)alloc(524288 * 4);
    float* mn2   = (float*)alloc(524288 * 4);
    float* h31   = (float*)alloc(524288 * 4);
    float* mx3   = (float*)alloc(8192 * 4);
    float* mn3   = (float*)alloc(8192 * 4);
    float* stats = (float*)alloc(129024 * 4);
    float* st1a = stats;                 // 16*2*64
    float* st2a = st1a + 2048;           // 64*2*128
    float* st1b = st2a + 16384;          // 16*2*128
    float* st2b = st1b + 4096;           // 64*2*256
    float* st3a = st2b + 32768;          // 16*2*256
    float* st3b = st3a + 8192;           // 64*2*512
    unsigned short* w12t = (unsigned short*)alloc(128 * 64 * 2);
    unsigned short* w22t = (unsigned short*)alloc(256 * 128 * 2);
    unsigned short* w32t = (unsigned short*)alloc(512 * 256 * 2);
    float* sc1 = (float*)alloc(64 * 4);   float* sh1 = (float*)alloc(64 * 4);
    float* sc2 = (float*)alloc(128 * 4);  float* sh2 = (float*)alloc(128 * 4);
    float* sc3 = (float*)alloc(256 * 4);  float* sh3 = (float*)alloc(256 * 4);

    hipMemsetAsync(stats, 0, 129024 * sizeof(float), stream);

    // weight transposes (independent of data flow)
    w2t_kernel<<<(64 * 128 + 255) / 256, 256, 0, stream>>>(w12, 64, 128, w12t);
    w2t_kernel<<<(128 * 256 + 255) / 256, 256, 0, stream>>>(w22, 128, 256, w22t);
    w2t_kernel<<<(256 * 512 + 255) / 256, 256, 0, stream>>>(w32, 256, 512, w32t);

    // ---- SA1 ----
    fps_kernel<4096, 256, 512><<<16, 512, 0, stream>>>(l0_xyz, 3 * 4096, 4096, 1, nxyz1, o_l1xyz);
    project6_kernel<<<16384, 256, 0, stream>>>(l0_xyz, l0_pts, w11, b11, p1);
    ballquery_kernel<32><<<4096, 64, 0, stream>>>(l0_xyz, 3 * 4096, 4096, 1, 4096,
                                                  nxyz1, 256, 0.04f, gi1, w11, 64, q1);
    stats_gather_kernel<<<256, 256, 0, stream>>>(p1, q1, gi1, 256, 32, 4096, 64, st1a);
    bnfin_kernel<<<1, 256, 0, stream>>>(st1a, 64, 131072.0f, g11, be11, sc1, sh1);
    mfma_gemm_kernel<32, 64, 128><<<4096, 512, 0, stream>>>(
        p1, q1, gi1, 256, 1, 4096, sc1, sh1, w12t, 128, b12, st2a, mx1, mn1);
    apply_kernel<<<128, 256, 0, stream>>>(st2a, 128, 131072.0f, g12, be12, mx1, mn1,
                                          256, feat1, o_l1pts, 524288, nullptr);

    // ---- SA2 ----
    fps_kernel<256, 128, 64><<<16, 64, 0, stream>>>(nxyz1, 768, 1, 3, nxyz2, o_l2xyz);
    proj_gemm_kernel<128><<<64, 512, 0, stream>>>(nxyz1, feat1, 256, 128, w21, 128, b21, p2);
    ballquery_kernel<64><<<2048, 64, 0, stream>>>(nxyz1, 768, 1, 3, 256,
                                                  nxyz2, 128, 0.0625f, gi2, w21, 128, q2);
    stats_gather_kernel<<<256, 256, 0, stream>>>(p2, q2, gi2, 128, 64, 256, 128, st1b);
    bnfin_kernel<<<1, 256, 0, stream>>>(st1b, 128, 131072.0f, g21, be21, sc2, sh2);
    mfma_gemm_kernel<64, 128, 256><<<2048, 512, 0, stream>>>(
        p2, q2, gi2, 128, 1, 256, sc2, sh2, w22t, 256, b22, st2b, mx2, mn2);
    apply_kernel<<<128, 256, 0, stream>>>(st2b, 256, 131072.0f, g22, be22, mx2, mn2,
                                          128, feat2, o_l2pts, 524288, nullptr);

    // ---- SA3 (group_all) ----
    proj_gemm_kernel<128><<<64, 512, 0, stream>>>(nxyz2, feat2, 128, 256, w31, 256, b31, h31);
    stats_raw_kernel<<<128, 256, 0, stream>>>(h31, 2048, 256, st3a);
    bnfin_kernel<<<1, 256, 0, stream>>>(st3a, 256, 2048.0f, g31, be31, sc3, sh3);
    mfma_gemm_kernel<128, 256, 128><<<64, 512, 0, stream>>>(
        h31, nullptr, nullptr, 1, 4, 0, sc3, sh3, w32t, 512, b32, st3b, mx3, mn3);
    apply_kernel<<<32, 256, 0, stream>>>(st3b, 512, 2048.0f, g32, be32, mx3, mn3,
                                         1, nullptr, o_x, 8192, o_l3xyz);
}

// Round 4
// 567.200 us; speedup vs baseline: 2.4869x; 1.4602x over previous
//
#include <hip/hip_runtime.h>
#include <cstddef>

// PointNet++ set-abstraction pipeline (B=16, N=4096, HC=64).
// R4: (1) FPS wave-reduce via DPP (row_shr/row_bcast, VALU-speed) instead of
// ds_bpermute shuffles; (2) heterogeneous mega-kernels: fps1 fused with
// project6/w2t/zeroing, fps2 fused with proj_gemm2 (fills idle CUs during
// latency-bound FPS); (3) BN1 stats fused into ball-query.

#define EPSB 1e-5f
constexpr int SLOTS1 = 16;
constexpr int SLOTS2 = 64;
constexpr int BATCH = 16;

static __device__ __forceinline__ unsigned long long umax64(unsigned long long a,
                                                            unsigned long long b)
{
    return a > b ? a : b;
}

static __device__ __forceinline__ unsigned pack_bf16x2(float a, float b)
{
    unsigned ua = __float_as_uint(a), ub = __float_as_uint(b);
    ua += 0x7fffu + ((ua >> 16) & 1u);
    ub += 0x7fffu + ((ub >> 16) & 1u);
    return (ua >> 16) | (ub & 0xffff0000u);
}

static __device__ __forceinline__ unsigned short bf16_of(float a)
{
    unsigned u = __float_as_uint(a);
    u += 0x7fffu + ((u >> 16) & 1u);
    return (unsigned short)(u >> 16);
}

// Full-wave (64-lane) u64 max reduce via DPP; returns the max broadcast to all
// lanes (via readlane 63). All lanes must be active. VALU-speed: ~10cyc/step.
static __device__ __forceinline__ unsigned long long wave_umax64_dpp(unsigned long long x)
{
#define DPP_STEP(ctrl, rmask)                                                        \
    {                                                                                \
        int lo_ = __builtin_amdgcn_update_dpp(0, (int)(unsigned)x, ctrl, rmask, 0xf, false); \
        int hi_ = __builtin_amdgcn_update_dpp(0, (int)(unsigned)(x >> 32), ctrl, rmask, 0xf, false); \
        unsigned long long c_ = ((unsigned long long)(unsigned)hi_ << 32) | (unsigned)lo_; \
        x = umax64(x, c_);                                                           \
    }
    DPP_STEP(0x111, 0xf)   // row_shr:1
    DPP_STEP(0x112, 0xf)   // row_shr:2
    DPP_STEP(0x114, 0xf)   // row_shr:4
    DPP_STEP(0x118, 0xf)   // row_shr:8  -> lane15 of each row has row max
    DPP_STEP(0x142, 0xa)   // row_bcast:15 into rows 1,3
    DPP_STEP(0x143, 0xc)   // row_bcast:31 into rows 2,3 -> lane 63 = wave max
#undef DPP_STEP
    unsigned lo = (unsigned)__builtin_amdgcn_readlane((int)(unsigned)x, 63);
    unsigned hi = (unsigned)__builtin_amdgcn_readlane((int)(unsigned)(x >> 32), 63);
    return ((unsigned long long)hi << 32) | lo;
}

// ---------------- FPS body ----------------
// jax scan semantics: idx[0]=0; dist=min(dist,|x-c|^2); next=argmax (first-index ties).
// Key: hi = float bits of dist (>=0), lo = ~gidx (max -> smallest index on ties).
template<int N, int NPOINT, int THREADS>
__device__ __forceinline__ void fps_body(char* smraw,
        const float* __restrict__ xyz, int bStride, int cStride, int nStride,
        int b, float* __restrict__ nxyz, float* __restrict__ lxyz)
{
    constexpr int PT = N / THREADS;
    constexpr int NW = THREADS / 64;
    const int t = threadIdx.x;
    float* sx = (float*)smraw;
    float* sy = sx + N;
    float* sz = sy + N;
    int* sel = (int*)(sz + N);
    unsigned long long* red = (unsigned long long*)(sel + NPOINT);  // [2][NW]
    const float* xb = xyz + (size_t)b * bStride;

    float px[PT], py[PT], pz[PT], dist[PT];
#pragma unroll
    for (int i = 0; i < PT; ++i) {
        int p = t + i * THREADS;
        px[i] = xb[(size_t)0 * cStride + (size_t)p * nStride];
        py[i] = xb[(size_t)1 * cStride + (size_t)p * nStride];
        pz[i] = xb[(size_t)2 * cStride + (size_t)p * nStride];
        sx[p] = px[i]; sy[p] = py[i]; sz[p] = pz[i];
        dist[i] = 1e10f;
    }
    if (t == 0) sel[0] = 0;
    if constexpr (NW > 1) __syncthreads();

    float cx = sx[0], cy = sy[0], cz = sz[0];
    for (int it = 1; it < NPOINT; ++it) {
        unsigned long long best = 0ull;
#pragma unroll
        for (int i = 0; i < PT; ++i) {
            float dx = px[i] - cx, dy = py[i] - cy, dz = pz[i] - cz;
            float d = __builtin_fmaf(dx, dx, __builtin_fmaf(dy, dy, dz * dz));
            float nd = fminf(dist[i], d);
            dist[i] = nd;
            unsigned long long k =
                ((unsigned long long)__float_as_uint(nd) << 32) |
                (unsigned int)(~(t + i * THREADS));
            best = umax64(best, k);
        }
        best = wave_umax64_dpp(best);   // uniform across the wave
        int widx;
        if constexpr (NW > 1) {
            const int pb = it & 1;
            if ((t & 63) == 0) red[pb * NW + (t >> 6)] = best;
            __syncthreads();
            unsigned long long m = red[pb * NW + 0];
#pragma unroll
            for (int w = 1; w < NW; ++w) m = umax64(m, red[pb * NW + w]);
            widx = (int)(~(unsigned int)m);
        } else {
            widx = (int)(~(unsigned int)best);
        }
        if (t == 0) sel[it] = widx;
        cx = sx[widx]; cy = sy[widx]; cz = sz[widx];
    }
    if constexpr (NW > 1) __syncthreads();
    for (int s = t; s < NPOINT; s += THREADS) {
        int id = sel[s];
        float X = sx[id], Y = sy[id], Z = sz[id];
        nxyz[(size_t)(b * NPOINT + s) * 3 + 0] = X;
        nxyz[(size_t)(b * NPOINT + s) * 3 + 1] = Y;
        nxyz[(size_t)(b * NPOINT + s) * 3 + 2] = Z;
        lxyz[(size_t)b * 3 * NPOINT + 0 * NPOINT + s] = X;
        lxyz[(size_t)b * 3 * NPOINT + 1 * NPOINT + s] = Y;
        lxyz[(size_t)b * 3 * NPOINT + 2 * NPOINT + s] = Z;
    }
}

// ---------------- Tiled projection GEMM body (512 threads) ----------------
template<int COUTB>
__device__ __forceinline__ void proj_gemm_body(char* smraw, int blk,
        const float* __restrict__ xyzsrc, const float* __restrict__ featsrc,
        int N, int CF, const float* __restrict__ W, int coutFull,
        const float* __restrict__ bias, float* __restrict__ outp)
{
    constexpr int BK = 32, BKP = 36, TK = 4, TC = 4, THREADS = 512, ROWS = 64;
    constexpr int C2G = COUTB / TC;
    static_assert(C2G * (ROWS / TK) == THREADS, "thread shape");
    float (*al)[BKP] = (float (*)[BKP])smraw;
    float (*wl)[BKP] = (float (*)[BKP])(smraw + ROWS * BKP * 4);
    const int NCH = coutFull / COUTB;
    const int chunk = blk % NCH;
    const int rb = blk / NCH;
    const int m0 = rb * ROWS;
    const int c2_0 = chunk * COUTB;
    const int K = CF + 3;
    const int tid = threadIdx.x;
    const int c2g = tid % C2G, kt = tid / C2G;
    float acc[TK][TC];
#pragma unroll
    for (int i = 0; i < TK; ++i)
#pragma unroll
        for (int j = 0; j < TC; ++j) acc[i][j] = 0.f;
    const int npan = (K + BK - 1) / BK;
    for (int pan = 0; pan < npan; ++pan) {
        __syncthreads();
        const int cbase = pan * BK;
        for (int e = tid; e < ROWS * BK; e += THREADS) {
            int rl = e / BK, cl = e % BK;
            int c = cbase + cl;
            int m = m0 + rl;
            int bb = m / N, n = m % N;
            float v = 0.f;
            if (c < 3) v = xyzsrc[(size_t)(bb * N + n) * 3 + c];
            else if (c < K) v = featsrc[(size_t)(bb * N + n) * CF + (c - 3)];
            al[rl][cl] = v;
        }
        for (int e = tid; e < COUTB * BK; e += THREADS) {
            int c2 = e % COUTB, cl = e / COUTB;
            int c = cbase + cl;
            wl[c2][cl] = (c < K) ? W[(size_t)c * coutFull + c2_0 + c2] : 0.f;
        }
        __syncthreads();
#pragma unroll
        for (int cl = 0; cl < BK; cl += 4) {
            float4 av[TK], wv[TC];
#pragma unroll
            for (int i = 0; i < TK; ++i) av[i] = *(const float4*)&al[kt * TK + i][cl];
#pragma unroll
            for (int j = 0; j < TC; ++j) wv[j] = *(const float4*)&wl[c2g + j * C2G][cl];
#pragma unroll
            for (int i = 0; i < TK; ++i)
#pragma unroll
                for (int j = 0; j < TC; ++j)
                    acc[i][j] += av[i].x * wv[j].x + av[i].y * wv[j].y
                               + av[i].z * wv[j].z + av[i].w * wv[j].w;
        }
    }
#pragma unroll
    for (int j = 0; j < TC; ++j) {
        float bb_ = bias[c2_0 + c2g + j * C2G];
#pragma unroll
        for (int i = 0; i < TK; ++i) {
            int m = m0 + kt * TK + i;
            outp[(size_t)m * coutFull + c2_0 + c2g + j * C2G] = acc[i][j] + bb_;
        }
    }
}

// ---------------- Mega-kernel 1: fps1 + project6 + w2t x3 + stats-zero ----------------
__global__ __launch_bounds__(512)
void mega1_kernel(const float* __restrict__ l0_xyz, const float* __restrict__ l0_pts,
                  const float* __restrict__ w11, const float* __restrict__ b11,
                  float* __restrict__ p1,
                  float* __restrict__ nxyz1, float* __restrict__ o_l1xyz,
                  const float* __restrict__ w12, unsigned short* __restrict__ w12t,
                  const float* __restrict__ w22, unsigned short* __restrict__ w22t,
                  const float* __restrict__ w32, unsigned short* __restrict__ w32t,
                  float* __restrict__ stats)
{
    __shared__ __attribute__((aligned(16))) char arena[50304];
    int blk = blockIdx.x;
    const int tid = threadIdx.x;
    if (blk < 16) {   // FPS SA1 (latency-bound; dispatched first)
        fps_body<4096, 256, 512>(arena, l0_xyz, 3 * 4096, 4096, 1, blk, nxyz1, o_l1xyz);
        return;
    }
    blk -= 16;
    if (blk < 8192) {  // project6: p1[b,n,64] = [xyz,pts]·W1 + b1
        int idx = blk * 512 + tid;
        int d = idx & 63;
        int n = (idx >> 6) & 4095;
        int b = idx >> 18;
        const float* xb = l0_xyz + (size_t)b * 3 * 4096 + n;
        const float* pb = l0_pts + (size_t)b * 3 * 4096 + n;
        float a0 = xb[0], a1 = xb[4096], a2 = xb[2 * 4096];
        float a3 = pb[0], a4 = pb[4096], a5 = pb[2 * 4096];
        float acc = b11[d];
        acc += a0 * w11[d] + a1 * w11[64 + d] + a2 * w11[128 + d];
        acc += a3 * w11[192 + d] + a4 * w11[256 + d] + a5 * w11[320 + d];
        p1[idx] = acc;
        return;
    }
    blk -= 8192;
    if (blk < 16) {    // w12t: 64x128
        int i = blk * 512 + tid;
        if (i < 64 * 128) { int k = i / 128, n = i % 128; w12t[(size_t)n * 64 + k] = bf16_of(w12[i]); }
        return;
    }
    blk -= 16;
    if (blk < 64) {    // w22t: 128x256
        int i = blk * 512 + tid;
        if (i < 128 * 256) { int k = i / 256, n = i % 256; w22t[(size_t)n * 128 + k] = bf16_of(w22[i]); }
        return;
    }
    blk -= 64;
    if (blk < 256) {   // w32t: 256x512
        int i = blk * 512 + tid;
        if (i < 256 * 512) { int k = i / 512, n = i % 512; w32t[(size_t)n * 256 + k] = bf16_of(w32[i]); }
        return;
    }
    blk -= 256;
    {                  // zero the stats arena (replaces hipMemsetAsync)
        int i = blk * 512 + tid;
        if (i < 129024) stats[i] = 0.f;
    }
}

// ---------------- Mega-kernel 2: fps2 + proj_gemm SA2 ----------------
__global__ __launch_bounds__(512)
void mega2_kernel(const float* __restrict__ nxyz1, float* __restrict__ nxyz2,
                  float* __restrict__ o_l2xyz,
                  const float* __restrict__ feat1, const float* __restrict__ w21,
                  const float* __restrict__ b21, float* __restrict__ p2)
{
    __shared__ __attribute__((aligned(16))) char arena[27648];
    if (blockIdx.x < 16) {
        if (threadIdx.x < 64)   // single-wave FPS (no barriers in NW==1 path)
            fps_body<256, 128, 64>(arena, nxyz1, 768, 1, 3, blockIdx.x, nxyz2, o_l2xyz);
        return;
    }
    proj_gemm_body<128>(arena, blockIdx.x - 16, nxyz1, feat1, 256, 128, w21, 128, b21, p2);
}

// ---------------- SA3 projection GEMM wrapper ----------------
__global__ __launch_bounds__(512)
void proj_gemm3_kernel(const float* __restrict__ xyzsrc, const float* __restrict__ featsrc,
                       int N, int CF, const float* __restrict__ W, int coutFull,
                       const float* __restrict__ bias, float* __restrict__ outp)
{
    __shared__ __attribute__((aligned(16))) char arena[27648];
    proj_gemm_body<128>(arena, blockIdx.x, xyzsrc, featsrc, N, CF, W, coutFull, bias, outp);
}

// ---------------- Ball query + q projection + fused BN1 stats ----------------
template<int NS, int D>
__global__ __launch_bounds__(64)
void ballstat_kernel(const float* __restrict__ xyz, int bStride, int cStride, int nStride, int N,
                     const float* __restrict__ nxyz, int S, float r2,
                     int* __restrict__ gi,
                     const float* __restrict__ W, float* __restrict__ q,
                     const float* __restrict__ p, float* __restrict__ slots)
{
    constexpr int DL = D / 64;
    __shared__ int sgo[NS];
    int bs = blockIdx.x;
    int b = bs / S;
    int l = threadIdx.x;
    float cx = nxyz[(size_t)bs * 3 + 0], cy = nxyz[(size_t)bs * 3 + 1], cz = nxyz[(size_t)bs * 3 + 2];
    float s2 = cx * cx + cy * cy + cz * cz;
    const float* xb = xyz + (size_t)b * bStride;
    int cnt = 0;
    int first = N - 1;
    int* go = gi + (size_t)bs * NS;
    for (int base = 0; base < N; base += 64) {
        int n = base + l;
        float x = xb[(size_t)0 * cStride + (size_t)n * nStride];
        float y = xb[(size_t)1 * cStride + (size_t)n * nStride];
        float z = xb[(size_t)2 * cStride + (size_t)n * nStride];
        float x2 = x * x + y * y + z * z;
        float dot = cx * x + cy * y + cz * z;
        float sqr = (s2 + x2) - 2.0f * dot;   // reference expansion form
        bool pass = (sqr <= r2);
        unsigned long long m = __ballot(pass);
        if (cnt == 0 && m) first = base + (__ffsll((unsigned long long)m) - 1);
        int pos = cnt + __popcll(m & ((1ull << l) - 1ull));
        if (pass && pos < NS) { go[pos] = n; sgo[pos] = n; }
        cnt += __popcll(m);
        if (cnt >= NS) break;
    }
    if (cnt < NS && l >= cnt && l < NS) { go[l] = first; sgo[l] = first; }

    // center projection q (kept in regs for the stats pass)
    float qv[DL];
#pragma unroll
    for (int j = 0; j < DL; ++j) {
        int d = j * 64 + l;
        qv[j] = cx * W[d] + cy * W[D + d] + cz * W[2 * D + d];
        q[(size_t)bs * D + d] = qv[j];
    }

    // fused BN1 statistics over this ball's gathered rows
    float s[DL], ss[DL];
#pragma unroll
    for (int j = 0; j < DL; ++j) { s[j] = 0.f; ss[j] = 0.f; }
    for (int k = 0; k < NS; ++k) {
        int idx = sgo[k];
        const float* pr = p + (size_t)(b * N + idx) * D;
#pragma unroll
        for (int j = 0; j < DL; ++j) {
            float v = pr[j * 64 + l] - qv[j];
            s[j] += v; ss[j] += v * v;
        }
    }
    int slot = bs & (SLOTS1 - 1);
#pragma unroll
    for (int j = 0; j < DL; ++j) {
        int d = j * 64 + l;
        atomicAdd(&slots[(size_t)(slot * 2 + 0) * D + d], s[j]);
        atomicAdd(&slots[(size_t)(slot * 2 + 1) * D + d], ss[j]);
    }
}

// ---------------- BN1 statistics over raw rows (SA3) ----------------
__global__ __launch_bounds__(256)
void stats_raw_kernel(const float* __restrict__ h, int M, int C, float* __restrict__ slots)
{
    int c = threadIdx.x;   // C == 256
    float sum = 0.f, sq = 0.f;
    for (int m = blockIdx.x; m < M; m += gridDim.x) {
        float v = h[(size_t)m * C + c];
        sum += v; sq += v * v;
    }
    int slot = blockIdx.x & (SLOTS1 - 1);
    atomicAdd(&slots[(size_t)(slot * 2 + 0) * C + c], sum);
    atomicAdd(&slots[(size_t)(slot * 2 + 1) * C + c], sq);
}

// ---------------- Finalize BN1 -> scale/shift arrays ----------------
__global__ __launch_bounds__(256)
void bnfin_kernel(const float* __restrict__ st, int C, float cnt,
                  const float* __restrict__ g, const float* __restrict__ be,
                  float* __restrict__ sc, float* __restrict__ sh)
{
    int c = blockIdx.x * 256 + threadIdx.x;
    if (c >= C) return;
    float s0 = 0.f, s1 = 0.f;
    for (int sl = 0; sl < SLOTS1; ++sl) {
        s0 += st[(size_t)(sl * 2 + 0) * C + c];
        s1 += st[(size_t)(sl * 2 + 1) * C + c];
    }
    float mean = s0 / cnt;
    float var = s1 / cnt - mean * mean;
    float inv = 1.0f / sqrtf(var + EPSB);
    float s = g[c] * inv;
    sc[c] = s;
    sh[c] = be[c] - s * mean;
}

// ---------------- MFMA layer-2 (unchanged from R3) ----------------
template<int KS, int CIN, int COUTB>
__global__ __launch_bounds__(512)
void mfma_gemm_kernel(const float* __restrict__ p, const float* __restrict__ q,
                      const int* __restrict__ gi, int S, int NCH, int N,
                      const float* __restrict__ bnsc, const float* __restrict__ bnsh,
                      const unsigned short* __restrict__ w2t, int coutFull,
                      const float* __restrict__ b2,
                      float* __restrict__ st2,
                      float* __restrict__ mx, float* __restrict__ mn)
{
    constexpr int MT = KS / 16;
    constexpr int NSL = 8 / MT;
    constexpr int SLW = COUTB / NSL;
    constexpr int TPW = SLW / 16;
    constexpr int KST = CIN / 32;
    constexpr int LDA = CIN + 8;
    typedef __attribute__((ext_vector_type(8))) short bf16x8;
    typedef __attribute__((ext_vector_type(4))) float f32x4;

    __shared__ __attribute__((aligned(16))) unsigned short hl[KS][LDA];
    __shared__ float red[4][8][SLW];

    const int chunk = blockIdx.x % NCH;
    const int bs = blockIdx.x / NCH;
    const int b = bs / S;
    const int tid = threadIdx.x;
    const int c2_0 = chunk * COUTB;
    const int w = tid >> 6, lane = tid & 63;
    const int mt = w % MT, ns = w / MT;
    const int lrow = lane & 15, quad = lane >> 4;

    constexpr int ITER = KS * CIN / (512 * 4);
    const int gbase = bs * KS;
#pragma unroll
    for (int it = 0; it < ITER; ++it) {
        int e = (it * 512 + tid) * 4;
        int k = e / CIN, c = e % CIN;
        int row = gi ? (b * N + gi[gbase + k]) : (b * KS + k);
        float4 v = *(const float4*)&p[(size_t)row * CIN + c];
        if (q) {
            float4 qq = *(const float4*)&q[(size_t)bs * CIN + c];
            v.x -= qq.x; v.y -= qq.y; v.z -= qq.z; v.w -= qq.w;
        }
        float4 sc = *(const float4*)&bnsc[c];
        float4 sh = *(const float4*)&bnsh[c];
        v.x = fmaxf(__builtin_fmaf(sc.x, v.x, sh.x), 0.f);
        v.y = fmaxf(__builtin_fmaf(sc.y, v.y, sh.y), 0.f);
        v.z = fmaxf(__builtin_fmaf(sc.z, v.z, sh.z), 0.f);
        v.w = fmaxf(__builtin_fmaf(sc.w, v.w, sh.w), 0.f);
        uint2 pk;
        pk.x = pack_bf16x2(v.x, v.y);
        pk.y = pack_bf16x2(v.z, v.w);
        *(uint2*)&hl[k][c] = pk;
    }
    __syncthreads();

    f32x4 acc[TPW];
#pragma unroll
    for (int t = 0; t < TPW; ++t) acc[t] = (f32x4){0.f, 0.f, 0.f, 0.f};

    const int nbase = c2_0 + ns * SLW + lrow;
#pragma unroll
    for (int ks = 0; ks < KST; ++ks) {
        bf16x8 a = *(const bf16x8*)&hl[mt * 16 + lrow][ks * 32 + quad * 8];
#pragma unroll
        for (int t = 0; t < TPW; ++t) {
            bf16x8 bfr = *(const bf16x8*)&w2t[(size_t)(nbase + t * 16) * CIN + ks * 32 + quad * 8];
            acc[t] = __builtin_amdgcn_mfma_f32_16x16x32_bf16(a, bfr, acc[t], 0, 0, 0);
        }
    }

#pragma unroll
    for (int t = 0; t < TPW; ++t) {
        float bias = b2[nbase + t * 16];
        float s = 0.f, sq = 0.f, amx = -3.4e38f, amn = 3.4e38f;
#pragma unroll
        for (int r = 0; r < 4; ++r) {
            float v = acc[t][r] + bias;
            s += v; sq += v * v;
            amx = fmaxf(amx, v); amn = fminf(amn, v);
        }
#pragma unroll
        for (int off = 16; off < 64; off <<= 1) {
            s += __shfl_xor(s, off);
            sq += __shfl_xor(sq, off);
            amx = fmaxf(amx, __shfl_xor(amx, off));
            amn = fminf(amn, __shfl_xor(amn, off));
        }
        if (quad == 0) {
            int lc = t * 16 + lrow;
            red[0][w][lc] = s; red[1][w][lc] = sq;
            red[2][w][lc] = amx; red[3][w][lc] = amn;
        }
    }
    __syncthreads();
    for (int c = tid; c < COUTB; c += 512) {
        int ns2 = c / SLW, lc = c % SLW;
        float s = 0.f, sq = 0.f, amx = -3.4e38f, amn = 3.4e38f;
#pragma unroll
        for (int m2 = 0; m2 < MT; ++m2) {
            int w2 = ns2 * MT + m2;
            s += red[0][w2][lc]; sq += red[1][w2][lc];
            amx = fmaxf(amx, red[2][w2][lc]);
            amn = fminf(amn, red[3][w2][lc]);
        }
        int slot = blockIdx.x & (SLOTS2 - 1);
        atomicAdd(&st2[(size_t)(slot * 2 + 0) * coutFull + c2_0 + c], s);
        atomicAdd(&st2[(size_t)(slot * 2 + 1) * coutFull + c2_0 + c], sq);
        mx[(size_t)bs * coutFull + c2_0 + c] = amx;
        mn[(size_t)bs * coutFull + c2_0 + c] = amn;
    }
}

// ---------------- Finalize BN2, apply to extrema, ReLU, write outputs ----------------
__global__ __launch_bounds__(256)
void apply_kernel(const float* __restrict__ st2, int C, float m2count,
                  const float* __restrict__ g2, const float* __restrict__ be2,
                  const float* __restrict__ mx, const float* __restrict__ mn,
                  int S, float* __restrict__ feat, float* __restrict__ outT,
                  int total, float* __restrict__ zero48)
{
    __shared__ float sc[512], sh[512];
    for (int c = threadIdx.x; c < C; c += 256) {
        float s0 = 0.f, s1 = 0.f;
        for (int sl = 0; sl < SLOTS2; ++sl) {
            s0 += st2[(size_t)(sl * 2 + 0) * C + c];
            s1 += st2[(size_t)(sl * 2 + 1) * C + c];
        }
        float mean = s0 / m2count;
        float var = s1 / m2count - mean * mean;
        float inv = 1.0f / sqrtf(var + EPSB);
        float scl = g2[c] * inv;
        sc[c] = scl; sh[c] = be2[c] - scl * mean;
    }
    __syncthreads();
    if (zero48 && blockIdx.x == 0 && threadIdx.x < 48) zero48[threadIdx.x] = 0.f;
    for (int e = blockIdx.x * 256 + threadIdx.x; e < total; e += gridDim.x * 256) {
        int c = e % C;
        int s = (e / C) % S;
        int b = e / (C * S);
        float scl = sc[c];
        float v = (scl >= 0.f) ? mx[e] : mn[e];   // maxpool commutes through monotone BN
        float y = fmaxf(scl * v + sh[c], 0.f);
        if (feat) feat[e] = y;
        outT[((size_t)b * C + c) * S + s] = y;
    }
}

extern "C" void kernel_launch(void* const* d_in, const int* in_sizes, int n_in,
                              void* d_out, int out_size, void* d_ws, size_t ws_size,
                              hipStream_t stream)
{
    (void)in_sizes; (void)n_in; (void)out_size; (void)ws_size;
    const float* l0_xyz = (const float*)d_in[0];
    const float* l0_pts = (const float*)d_in[1];
    const float* w11 = (const float*)d_in[2];  const float* b11 = (const float*)d_in[3];
    const float* g11 = (const float*)d_in[4];  const float* be11 = (const float*)d_in[5];
    const float* w12 = (const float*)d_in[6];  const float* b12 = (const float*)d_in[7];
    const float* g12 = (const float*)d_in[8];  const float* be12 = (const float*)d_in[9];
    const float* w21 = (const float*)d_in[10]; const float* b21 = (const float*)d_in[11];
    const float* g21 = (const float*)d_in[12]; const float* be21 = (const float*)d_in[13];
    const float* w22 = (const float*)d_in[14]; const float* b22 = (const float*)d_in[15];
    const float* g22 = (const float*)d_in[16]; const float* be22 = (const float*)d_in[17];
    const float* w31 = (const float*)d_in[18]; const float* b31 = (const float*)d_in[19];
    const float* g31 = (const float*)d_in[20]; const float* be31 = (const float*)d_in[21];
    const float* w32 = (const float*)d_in[22]; const float* b32 = (const float*)d_in[23];
    const float* g32 = (const float*)d_in[24]; const float* be32 = (const float*)d_in[25];

    float* out = (float*)d_out;
    float* o_l1xyz = out;                 // (16,3,256)
    float* o_l1pts = out + 12288;         // (16,128,256)
    float* o_l2xyz = out + 536576;        // (16,3,128)
    float* o_l2pts = out + 542720;        // (16,256,128)
    float* o_l3xyz = out + 1067008;       // (16,3,1)
    float* o_x     = out + 1067056;       // (16,512)

    char* ws = (char*)d_ws;
    size_t off = 0;
    auto alloc = [&](size_t bytes) {
        void* r = ws + off;
        off += ((bytes + 255) & ~(size_t)255);
        return r;
    };
    float* nxyz1 = (float*)alloc(12288 * 4);
    float* nxyz2 = (float*)alloc(6144 * 4);
    int*   gi1   = (int*)alloc(131072 * 4);
    int*   gi2   = (int*)alloc(131072 * 4);
    float* p1    = (float*)alloc(4194304 * 4);
    float* q1    = (float*)alloc(262144 * 4);
    float* feat1 = (float*)alloc(524288 * 4);
    float* mx1   = (float*)alloc(524288 * 4);
    float* mn1   = (float*)alloc(524288 * 4);
    float* p2    = (float*)alloc(524288 * 4);
    float* q2    = (float*)alloc(262144 * 4);
    float* feat2 = (float*)alloc(524288 * 4);
    float* mx2   = (float*)alloc(524288 * 4);
    float* mn2   = (float*)alloc(524288 * 4);
    float* h31   = (float*)alloc(524288 * 4);
    float* mx3   = (float*)alloc(8192 * 4);
    float* mn3   = (float*)alloc(8192 * 4);
    float* stats = (float*)alloc(129024 * 4);
    float* st1a = stats;                 // 16*2*64
    float* st2a = st1a + 2048;           // 64*2*128
    float* st1b = st2a + 16384;          // 16*2*128
    float* st2b = st1b + 4096;           // 64*2*256
    float* st3a = st2b + 32768;          // 16*2*256
    float* st3b = st3a + 8192;           // 64*2*512
    unsigned short* w12t = (unsigned short*)alloc(128 * 64 * 2);
    unsigned short* w22t = (unsigned short*)alloc(256 * 128 * 2);
    unsigned short* w32t = (unsigned short*)alloc(512 * 256 * 2);
    float* sc1 = (float*)alloc(64 * 4);   float* sh1 = (float*)alloc(64 * 4);
    float* sc2 = (float*)alloc(128 * 4);  float* sh2 = (float*)alloc(128 * 4);
    float* sc3 = (float*)alloc(256 * 4);  float* sh3 = (float*)alloc(256 * 4);

    // ---- SA1 ----
    // mega1: fps1(16) + project6(8192) + w12t(16) + w22t(64) + w32t(256) + zero(252)
    mega1_kernel<<<8796, 512, 0, stream>>>(l0_xyz, l0_pts, w11, b11, p1,
                                           nxyz1, o_l1xyz,
                                           w12, w12t, w22, w22t, w32, w32t, stats);
    ballstat_kernel<32, 64><<<4096, 64, 0, stream>>>(l0_xyz, 3 * 4096, 4096, 1, 4096,
                                                     nxyz1, 256, 0.04f, gi1, w11, q1, p1, st1a);
    bnfin_kernel<<<1, 256, 0, stream>>>(st1a, 64, 131072.0f, g11, be11, sc1, sh1);
    mfma_gemm_kernel<32, 64, 128><<<4096, 512, 0, stream>>>(
        p1, q1, gi1, 256, 1, 4096, sc1, sh1, w12t, 128, b12, st2a, mx1, mn1);
    apply_kernel<<<128, 256, 0, stream>>>(st2a, 128, 131072.0f, g12, be12, mx1, mn1,
                                          256, feat1, o_l1pts, 524288, nullptr);

    // ---- SA2 ----
    // mega2: fps2(16) + proj_gemm2(64)
    mega2_kernel<<<80, 512, 0, stream>>>(nxyz1, nxyz2, o_l2xyz, feat1, w21, b21, p2);
    ballstat_kernel<64, 128><<<2048, 64, 0, stream>>>(nxyz1, 768, 1, 3, 256,
                                                      nxyz2, 128, 0.0625f, gi2, w21, q2, p2, st1b);
    bnfin_kernel<<<1, 256, 0, stream>>>(st1b, 128, 131072.0f, g21, be21, sc2, sh2);
    mfma_gemm_kernel<64, 128, 256><<<2048, 512, 0, stream>>>(
        p2, q2, gi2, 128, 1, 256, sc2, sh2, w22t, 256, b22, st2b, mx2, mn2);
    apply_kernel<<<128, 256, 0, stream>>>(st2b, 256, 131072.0f, g22, be22, mx2, mn2,
                                          128, feat2, o_l2pts, 524288, nullptr);

    // ---- SA3 (group_all) ----
    proj_gemm3_kernel<<<64, 512, 0, stream>>>(nxyz2, feat2, 128, 256, w31, 256, b31, h31);
    stats_raw_kernel<<<128, 256, 0, stream>>>(h31, 2048, 256, st3a);
    bnfin_kernel<<<1, 256, 0, stream>>>(st3a, 256, 2048.0f, g31, be31, sc3, sh3);
    mfma_gemm_kernel<128, 256, 128><<<64, 512, 0, stream>>>(
        h31, nullptr, nullptr, 1, 4, 0, sc3, sh3, w32t, 512, b32, st3b, mx3, mn3);
    apply_kernel<<<32, 256, 0, stream>>>(st3b, 512, 2048.0f, g32, be32, mx3, mn3,
                                         1, nullptr, o_x, 8192, o_l3xyz);
}